// Round 1
// 416.078 us; speedup vs baseline: 1.0603x; 1.0603x over previous
//
#include <hip/hip_runtime.h>
#include <cstdint>

typedef unsigned short u16;

constexpr int BATCH = 128;
constexpr int H = 512, W = 512;
constexpr int HW = H * W;       // 2^18
constexpr int WPR = W / 64;     // 8 words per row
constexpr int WPI = HW / 64;    // 4096 words per image
constexpr int NSEED = 1000;
constexpr int MARGIN = 3000;    // expected candidate count for threshold select
constexpr int CAP2 = 4096;      // per-image candidate list capacity
constexpr int CAPS = 1024;      // tie list capacity (mean ~64)
constexpr int LBUF = 2048;      // per-block LDS candidate buffer
constexpr int NBIN = 4096;      // gh stride; bins 0..4079 used (g = floor(v*4080))

// ---------------- Threefry-2x32 (20 rounds), bit-exact vs JAX ----------------
__device__ __forceinline__ uint32_t rotl32(uint32_t v, int d) {
  return (v << d) | (v >> (32 - d));
}

__device__ __forceinline__ void tf2x32(uint32_t k0, uint32_t k1,
                                       uint32_t x0, uint32_t x1,
                                       uint32_t &o0, uint32_t &o1) {
  uint32_t ks2 = k0 ^ k1 ^ 0x1BD11BDAu;
  x0 += k0; x1 += k1;
  x0 += x1; x1 = rotl32(x1, 13); x1 ^= x0;
  x0 += x1; x1 = rotl32(x1, 15); x1 ^= x0;
  x0 += x1; x1 = rotl32(x1, 26); x1 ^= x0;
  x0 += x1; x1 = rotl32(x1, 6);  x1 ^= x0;
  x0 += k1; x1 += ks2 + 1u;
  x0 += x1; x1 = rotl32(x1, 17); x1 ^= x0;
  x0 += x1; x1 = rotl32(x1, 29); x1 ^= x0;
  x0 += x1; x1 = rotl32(x1, 16); x1 ^= x0;
  x0 += x1; x1 = rotl32(x1, 24); x1 ^= x0;
  x0 += ks2; x1 += k0 + 2u;
  x0 += x1; x1 = rotl32(x1, 13); x1 ^= x0;
  x0 += x1; x1 = rotl32(x1, 15); x1 ^= x0;
  x0 += x1; x1 = rotl32(x1, 26); x1 ^= x0;
  x0 += x1; x1 = rotl32(x1, 6);  x1 ^= x0;
  x0 += k0; x1 += k1 + 3u;
  x0 += x1; x1 = rotl32(x1, 17); x1 ^= x0;
  x0 += x1; x1 = rotl32(x1, 29); x1 ^= x0;
  x0 += x1; x1 = rotl32(x1, 16); x1 ^= x0;
  x0 += x1; x1 = rotl32(x1, 24); x1 ^= x0;
  x0 += k1; x1 += ks2 + 4u;
  x0 += x1; x1 = rotl32(x1, 13); x1 ^= x0;
  x0 += x1; x1 = rotl32(x1, 15); x1 ^= x0;
  x0 += x1; x1 = rotl32(x1, 26); x1 ^= x0;
  x0 += x1; x1 = rotl32(x1, 6);  x1 ^= x0;
  x0 += ks2; x1 += k0 + 5u;
  o0 = x0; o1 = x1;
}

__device__ __forceinline__ uint32_t score_bits(uint32_t k0, uint32_t k1, uint32_t i) {
  uint32_t a, c; tf2x32(k0, k1, 0u, i, a, c);
  return a ^ c;
}

// ---------------- per-image keys + nbr_bg + bg score threshold ----------------
__device__ __forceinline__ void keygen(int b, uint32_t* keys, uint32_t* kbg,
                                       uint32_t* Tbg) {
  uint32_t kb0, kb1; tf2x32(0u, 42u, 0u, (uint32_t)b, kb0, kb1);
  uint32_t kf0, kf1; tf2x32(kb0, kb1, 0u, 0u, kf0, kf1);
  uint32_t kB0, kB1; tf2x32(kb0, kb1, 0u, 1u, kB0, kB1);
  uint32_t kz0, kz1; tf2x32(kb0, kb1, 0u, 2u, kz0, kz1);
  uint32_t za, zc; tf2x32(kz0, kz1, 0u, 0u, za, zc);
  uint32_t zb = za ^ zc;
  keys[b * 4 + 0] = kf0; keys[b * 4 + 1] = kf1;
  keys[b * 4 + 2] = kB0; keys[b * 4 + 3] = kB1;
  float uu = __uint_as_float((zb >> 9) | 0x3f800000u) - 1.0f;
  float span = __fsub_rn(0.7f, 0.3f);
  float z = __fadd_rn(__fmul_rn(uu, span), 0.3f);
  z = fmaxf(0.3f, z);
  float nb = ceilf(__fmul_rn(z, (float)HW));
  uint32_t K = (uint32_t)nb;
  kbg[b] = K;
  float tv = floorf((1.0f - (float)MARGIN / (float)K) * 8388608.0f);
  Tbg[b] = (uint32_t)fmaxf(tv, 0.0f);
}

// -------- fused x sweep: single 4080-bin hist + packed u16 bin output --------
// g = floor(v*4080) clamped to [0,4079].  Exactness: RN(v*4080)=RN(v*255)*16
// (power-of-2 scaling commutes with rounding), so g>>4 == clip(floor(v*255)).
__global__ __launch_bounds__(1024) void k_binify(const float4* __restrict__ x4,
                                                 u16* __restrict__ g,
                                                 uint32_t* __restrict__ gh,
                                                 uint32_t* __restrict__ keys,
                                                 uint32_t* __restrict__ kbg,
                                                 uint32_t* __restrict__ Tbg) {
  __shared__ uint32_t h[NBIN];
  int b = blockIdx.x >> 2, sub = blockIdx.x & 3, t = threadIdx.x;
  if (blockIdx.x == 0 && t < BATCH) keygen(t, keys, kbg, Tbg);  // fused k_keys
  for (int i = t; i < NBIN; i += 1024) h[i] = 0;
  __syncthreads();
  const float4* xb = x4 + ((size_t)b * HW + (size_t)sub * (HW / 4)) / 4;
  ushort4* gb4 = (ushort4*)g + ((size_t)b * HW + (size_t)sub * (HW / 4)) / 4;
  for (int i = t; i < HW / 16; i += 1024) {
    float4 v4 = xb[i];
    int g0 = (int)floorf(__fmul_rn(v4.x, 4080.0f)); g0 = min(max(g0, 0), 4079);
    int g1 = (int)floorf(__fmul_rn(v4.y, 4080.0f)); g1 = min(max(g1, 0), 4079);
    int g2 = (int)floorf(__fmul_rn(v4.z, 4080.0f)); g2 = min(max(g2, 0), 4079);
    int g3 = (int)floorf(__fmul_rn(v4.w, 4080.0f)); g3 = min(max(g3, 0), 4079);
    atomicAdd(&h[g0], 1u);
    atomicAdd(&h[g1], 1u);
    atomicAdd(&h[g2], 1u);
    atomicAdd(&h[g3], 1u);
    ushort4 o;
    o.x = (u16)g0; o.y = (u16)g1; o.z = (u16)g2; o.w = (u16)g3;
    gb4[i] = o;
  }
  __syncthreads();
  for (int i = t; i < NBIN; i += 1024)
    if (h[i]) atomicAdd(&gh[(size_t)b * NBIN + i], h[i]);
}

// ------- fused Otsu (blocks 0..127, h256 from gh group-sums) + K-scan -------
__device__ __forceinline__ void lds_tree_cumsum256(float* L, float* S, int tid) {
  const int off[9] = {0, 256, 384, 448, 480, 496, 504, 508, 510};
  const int sz[9]  = {256, 128, 64, 32, 16, 8, 4, 2, 1};
  for (int l = 0; l < 8; ++l) {
    int o = off[l], on = off[l + 1], n = sz[l + 1];
    if (tid < n) L[on + tid] = __fadd_rn(L[o + 2 * tid], L[o + 2 * tid + 1]);
    __syncthreads();
  }
  if (tid == 0) S[off[8]] = L[off[8]];
  __syncthreads();
  for (int l = 7; l >= 0; --l) {
    int o = off[l], on = off[l + 1], hn = sz[l] / 2;
    if (tid == 0) S[o] = L[o];
    if (tid < hn) S[o + 2 * tid + 1] = S[on + tid];
    if (tid >= 1 && tid < hn) S[o + 2 * tid] = __fadd_rn(S[on + tid - 1], L[o + 2 * tid]);
    __syncthreads();
  }
}

__global__ __launch_bounds__(256) void k_otsu_scan(const uint32_t* __restrict__ gh,
                                                   const uint32_t* __restrict__ Ka,
                                                   int* __restrict__ th_out,
                                                   uint32_t* __restrict__ b1a,
                                                   uint32_t* __restrict__ r1a) {
  __shared__ float L[511], S[511], wc[256], mm[256];
  __shared__ float sv[256];
  __shared__ int si[256];
  __shared__ uint32_t h[NBIN];
  __shared__ uint32_t ps[256];
  int tid = threadIdx.x;
  if (blockIdx.x < BATCH) {
    int b = blockIdx.x;
    const uint32_t* gg = gh + (size_t)b * NBIN;
    for (int i = tid; i < NBIN; i += 256) h[i] = gg[i];
    __syncthreads();
    uint32_t hv = 0;
#pragma unroll
    for (int i = 0; i < 16; ++i) hv += h[tid * 16 + i];   // h256[tid], exact
    L[tid] = (float)hv;
    __syncthreads();
    lds_tree_cumsum256(L, S, tid);
    wc[tid] = S[tid];
    __syncthreads();
    L[tid] = __fmul_rn((float)hv, (float)tid);
    __syncthreads();
    lds_tree_cumsum256(L, S, tid);
    mm[tid] = S[tid];
    __syncthreads();
    float total = (float)HW;
    float mT = mm[255];
    {
      float w = wc[tid];
      float denom = __fmul_rn(w, __fsub_rn(total, w));
      float s = 0.0f;
      if (denom > 0.0f) {
        float d  = __fsub_rn(__fmul_rn(mT, w), __fmul_rn(total, mm[tid]));
        float nu = __fmul_rn(d, d);
        float dd = __fmul_rn(__fmul_rn(denom, total), total);
        s = __fdiv_rn(nu, dd);
      }
      sv[tid] = s; si[tid] = tid;
    }
    __syncthreads();
    for (int st = 128; st >= 1; st >>= 1) {
      if (tid < st) {
        float s2 = sv[tid + st]; int i2 = si[tid + st];
        if (s2 > sv[tid] || (s2 == sv[tid] && i2 < si[tid])) { sv[tid] = s2; si[tid] = i2; }
      }
      __syncthreads();
    }
    if (tid == 0) {
      int bi = si[0];
      if (bi == 0) bi = 1;
      if (bi == 255) bi = 254;
      th_out[b] = bi;
    }
  } else {
    int b = blockIdx.x - BATCH;
    uint32_t K = Ka[b];
    const uint32_t* g = gh + (size_t)b * NBIN;
    for (int i = tid; i < NBIN; i += 256) h[i] = g[i];
    __syncthreads();
    uint32_t s = 0;
#pragma unroll
    for (int i = 0; i < 16; ++i) s += h[tid * 16 + i];
    ps[tid] = s;
    __syncthreads();
    if (tid == 0) {
      uint32_t acc = 0, b1 = 0, r1 = 1;
      for (int c = 0; c < 256; ++c) {
        if (acc + ps[c] >= K) {
          for (int bin = c * 16; bin < c * 16 + 16; ++bin) {
            uint32_t cc = h[bin];
            if (acc + cc >= K) { b1 = (uint32_t)bin; r1 = K - acc; break; }
            acc += cc;
          }
          break;
        }
        acc += ps[c];
      }
      b1a[b] = b1; r1a[b] = r1;
    }
  }
}

// ==== mega-fused: ROI bits + 11x11 erosion + E count + bg elig compaction +
//      bg threefry candidates + bg tie collection. Consumes u16 bins.
__global__ __launch_bounds__(1024) void k_main(const u16* __restrict__ gq,
                                               const float* __restrict__ x,
                                               const int* __restrict__ th,
                                               const uint32_t* __restrict__ b1a,
                                               const uint32_t* __restrict__ Tbg,
                                               const uint32_t* __restrict__ keys,
                                               uint32_t* __restrict__ Efg,
                                               uint32_t* __restrict__ cnt_bg,
                                               uint64_t* __restrict__ list,
                                               uint32_t* __restrict__ cnt_be,
                                               uint64_t* __restrict__ list_be,
                                               uint64_t* __restrict__ erod) {
  __shared__ uint64_t sroi[1104];   // roi bits, slab rows (<=138) x 8 words
  __shared__ uint64_t srow[1104];   // after 11-wide row min
  __shared__ uint32_t queue[8192];  // per-tile eligible pixel queue (max 16*512)
  __shared__ uint64_t lbuf[LBUF];   // candidate keys
  __shared__ uint32_t qcnt, lcnt, gbase;
  int b = blockIdx.x >> 2, sub = blockIdx.x & 3, t = threadIdx.x;
  int wave = t >> 6, lane = t & 63;
  int R0 = sub * 128;
  int rlo = max(R0 - 5, 0), rhi = min(R0 + 133, H);
  int nrows = rhi - rlo;
  int nwords = nrows * 8;
  const u16* gb = gq + (size_t)b * HW;
  const float* xb = x + (size_t)b * HW;
  int groi = (th[b] + 1) << 4;     // g >= 16*(th+1)  <=>  floor(v*255) > th
  uint32_t b1 = b1a[b];
  uint32_t T = Tbg[b];
  uint32_t k0 = keys[b * 4 + 2], k1 = keys[b * 4 + 3];
  if (t == 0) lcnt = 0;
  __syncthreads();
  // phase A: tiles of 128 slab words (16 rows); roi ballot + compaction + drain
  int ntiles = (nwords + 127) / 128;
  for (int tile = 0; tile < ntiles; ++tile) {
    if (t == 0) qcnt = 0;
    __syncthreads();
    int wbeg = tile * 128, wend = min(wbeg + 128, nwords);
    for (int wi = wbeg + wave; wi < wend; wi += 16) {
      int srow_i = wi >> 3, c = wi & 7;
      int absr = rlo + srow_i;
      int p = absr * W + c * 64 + lane;
      uint32_t gv = (uint32_t)gb[p];
      bool pred = (int)gv >= groi;
      uint64_t bw = __ballot(pred);
      if (lane == 0) sroi[wi] = bw;
      if (absr >= R0 && absr < R0 + 128) {
        bool elig = gv < b1;
        uint64_t m = __ballot(elig);
        uint32_t base = 0;
        if (lane == 0 && m) base = atomicAdd(&qcnt, (uint32_t)__popcll(m));
        base = (uint32_t)__shfl((int)base, 0);
        if (elig) {
          uint32_t rank = (uint32_t)__popcll(m & ((1ull << lane) - 1ull));
          queue[base + rank] = (uint32_t)p;
        }
        if (gv == b1) {   // rare (~64/image): boundary bin, exact-value tie
          uint32_t gp = atomicAdd(&cnt_be[b], 1u);
          if (gp < (uint32_t)CAPS) {
            float v = xb[p];
            list_be[(size_t)b * CAPS + gp] =
                (((uint64_t)__float_as_uint(v)) << 18) | (uint32_t)p;
          }
        }
      }
    }
    __syncthreads();
    uint32_t qn = qcnt;
    for (uint32_t i = t; i < qn; i += 1024) {
      uint32_t p = queue[i];
      uint32_t v = score_bits(k0, k1, p) >> 9;
      if (v >= T) {
        uint32_t pos = atomicAdd(&lcnt, 1u);
        uint64_t key = (((uint64_t)((~v) & 0x7FFFFFu)) << 18) | p;
        if (pos < (uint32_t)LBUF) lbuf[pos] = key;
        else { uint32_t gp = atomicAdd(&cnt_bg[b], 1u);
               if (gp < (uint32_t)CAP2) list[(size_t)b * CAP2 + gp] = key; }
      }
    }
    __syncthreads();
  }
  // 11-wide row min over slab
  for (int wi = t; wi < nwords; wi += 1024) {
    int c = wi & 7;
    uint64_t cur = sroi[wi];
    uint64_t left  = (c > 0) ? sroi[wi - 1] : ~0ull;
    uint64_t right = (c < 7) ? sroi[wi + 1] : ~0ull;
    uint64_t res = cur;
#pragma unroll
    for (int s = 1; s <= 5; ++s) {
      res &= (cur >> s) | (right << (64 - s));
      res &= (cur << s) | (left >> (64 - s));
    }
    srow[wi] = res;
  }
  __syncthreads();
  // 11-tall col min for core rows (exactly 1024 words) + popcount
  {
    int coreRow = t >> 3, c = t & 7;
    int absr = R0 + coreRow;
    int s = absr - rlo;
    uint64_t res = srow[s * 8 + c];
#pragma unroll
    for (int d = 1; d <= 5; ++d) {
      if (absr - d >= 0) res &= srow[(s - d) * 8 + c];
      if (absr + d < H)  res &= srow[(s + d) * 8 + c];
    }
    erod[(size_t)b * WPI + absr * 8 + c] = res;
    uint32_t pc = (uint32_t)__popcll(res);
    for (int sh = 32; sh >= 1; sh >>= 1) pc += __shfl_down(pc, sh);
    if (lane == 0 && pc) atomicAdd(&Efg[b], pc);
  }
  __syncthreads();
  // bulk candidate append
  int m = min((int)lcnt, LBUF);
  if (t == 0) gbase = atomicAdd(&cnt_bg[b], (uint32_t)m);
  __syncthreads();
  uint32_t base = gbase;
  for (int i = t; i < m; i += 1024) {
    uint32_t pos = base + (uint32_t)i;
    if (pos < (uint32_t)CAP2) list[(size_t)b * CAP2 + pos] = lbuf[i];
  }
}

// ---- fused bg select: tie-rank extras (LDS-staged) + exact top-NSEED ----
__global__ __launch_bounds__(1024) void k_bgsel(const uint32_t* __restrict__ r1a,
                                                const uint32_t* __restrict__ cnt_be,
                                                const uint64_t* __restrict__ list_be,
                                                const uint32_t* __restrict__ Tbg,
                                                const uint32_t* __restrict__ keys,
                                                const uint32_t* __restrict__ cnt_bg,
                                                const uint64_t* __restrict__ list,
                                                uint64_t* __restrict__ bm) {
  __shared__ uint64_t ks[CAPS];
  __shared__ uint64_t ebuf[CAPS];
  __shared__ uint32_t ecnt;
  __shared__ uint32_t h[4096];
  __shared__ uint32_t S[256];
  __shared__ uint32_t sb2, sr2;
  __shared__ uint64_t tie[1024];
  __shared__ uint32_t tcnt;
  int b = blockIdx.x, t = threadIdx.x;
  int nbe = min((int)cnt_be[b], CAPS);
  if (t == 0) { ecnt = 0; tcnt = 0; }
  if (t < nbe) ks[t] = list_be[(size_t)b * CAPS + t];
  __syncthreads();
  if (t < nbe) {
    uint64_t mk = ks[t];
    int rank = 0;
    for (int i = 0; i < nbe; ++i) rank += (ks[i] < mk) ? 1 : 0;
    int r = min((int)r1a[b], nbe);
    if (rank < r) {
      uint32_t p = (uint32_t)(mk & 0x3FFFFull);
      uint32_t v = score_bits(keys[b * 4 + 2], keys[b * 4 + 3], p) >> 9;
      if (v >= Tbg[b]) {
        uint32_t slot = atomicAdd(&ecnt, 1u);
        ebuf[slot] = (((uint64_t)((~v) & 0x7FFFFFu)) << 18) | p;
      }
    }
  }
  for (int i = t; i < 4096; i += 1024) h[i] = 0;
  __syncthreads();
  int n0 = min((int)cnt_bg[b], CAP2);
  int ne = (int)ecnt;
  int n = n0 + ne;
  if (n == 0) return;
  uint32_t target = (uint32_t)min(NSEED, n);
  const uint64_t* lb = list + (size_t)b * CAP2;
  uint64_t K0 = (t < n0)        ? lb[t]        : 0;
  uint64_t K1 = (t + 1024 < n0) ? lb[t + 1024] : 0;
  uint64_t K2 = (t + 2048 < n0) ? lb[t + 2048] : 0;
  uint64_t K3 = (t + 3072 < n0) ? lb[t + 3072] : 0;
  uint64_t KE = (t < ne)        ? ebuf[t]      : 0;
  if (t < n0)        atomicAdd(&h[(uint32_t)(K0 >> 29)], 1u);
  if (t + 1024 < n0) atomicAdd(&h[(uint32_t)(K1 >> 29)], 1u);
  if (t + 2048 < n0) atomicAdd(&h[(uint32_t)(K2 >> 29)], 1u);
  if (t + 3072 < n0) atomicAdd(&h[(uint32_t)(K3 >> 29)], 1u);
  if (t < ne)        atomicAdd(&h[(uint32_t)(KE >> 29)], 1u);
  __syncthreads();
  if (t < 256) {
    uint32_t s = 0;
#pragma unroll
    for (int i = 0; i < 16; ++i) s += h[t * 16 + i];
    S[t] = s;
  }
  __syncthreads();
  for (int st = 1; st < 256; st <<= 1) {
    uint32_t v = 0;
    if (t < 256 && t >= st) v = S[t - st];
    __syncthreads();
    if (t < 256) S[t] += v;
    __syncthreads();
  }
  if (t < 256) {
    uint32_t before = (t == 0) ? 0u : S[t - 1];
    if (S[t] >= target && before < target) {
      uint32_t acc = before;
      for (int i = 0; i < 16; ++i) {
        uint32_t c = h[t * 16 + i];
        if (acc + c >= target) { sb2 = (uint32_t)(t * 16 + i); sr2 = target - acc; break; }
        acc += c;
      }
    }
  }
  __syncthreads();
  uint32_t b2 = sb2, r2 = sr2;
#define PROC(KK, VALID) \
  if (VALID) { \
    uint32_t bin = (uint32_t)((KK) >> 29); \
    if (bin < b2) { \
      uint32_t p = (uint32_t)(KK) & 0x3FFFFu; \
      atomicOr((unsigned long long*)&bm[(size_t)b * WPI + (p >> 6)], 1ull << (p & 63)); \
    } else if (bin == b2) { \
      uint32_t pos = atomicAdd(&tcnt, 1u); \
      if (pos < 1024u) tie[pos] = (KK); \
    } \
  }
  PROC(K0, t < n0) PROC(K1, t + 1024 < n0) PROC(K2, t + 2048 < n0)
  PROC(K3, t + 3072 < n0) PROC(KE, t < ne)
#undef PROC
  __syncthreads();
  int m = min((int)tcnt, 1024);
  int r = min((int)r2, m);
  if (t < m) {
    uint64_t mk = tie[t];
    int rank = 0;
    for (int i = 0; i < m; ++i) rank += (tie[i] < mk) ? 1 : 0;
    if (rank < r) {
      uint32_t p = (uint32_t)mk & 0x3FFFFu;
      atomicOr((unsigned long long*)&bm[(size_t)b * WPI + (p >> 6)], 1ull << (p & 63));
    }
  }
}

// ---- fg select sweep: T from Efg inline; copy path when E<=NSEED ----
__global__ __launch_bounds__(1024) void k_selfg(const uint64_t* __restrict__ elig,
                                                const uint32_t* __restrict__ keys,
                                                const uint32_t* __restrict__ Ea,
                                                uint32_t* __restrict__ cnt,
                                                uint64_t* __restrict__ list,
                                                uint64_t* __restrict__ out) {
  __shared__ uint64_t lbuf[LBUF];
  __shared__ uint32_t lcnt;
  __shared__ uint32_t gbase;
  int b = blockIdx.x >> 2, sub = blockIdx.x & 3, t = threadIdx.x;
  const uint64_t* eb = elig + (size_t)b * WPI;
  uint64_t* ob = out + (size_t)b * WPI;
  uint32_t E = Ea[b];
  int wbase = sub * (WPI / 4);
  if (E <= (uint32_t)NSEED) {     // all eligible selected
    for (int w = t; w < WPI / 4; w += 1024) ob[wbase + w] = eb[wbase + w];
    return;
  }
  float tvf = floorf((1.0f - (float)MARGIN / (float)E) * 8388608.0f);
  uint32_t T = (uint32_t)fmaxf(tvf, 0.0f);
  if (t == 0) lcnt = 0;
  for (int w = t; w < WPI / 4; w += 1024) ob[wbase + w] = 0;
  __syncthreads();
  uint32_t k0 = keys[b * 4 + 0], k1 = keys[b * 4 + 1];
  uint32_t pbase = (uint32_t)(sub * (HW / 4));
  for (int i = t; i < HW / 4; i += 2048) {
    uint32_t p1 = pbase + (uint32_t)i;
    uint32_t p2 = p1 + 1024u;
    uint32_t v1 = score_bits(k0, k1, p1) >> 9;
    uint32_t v2 = score_bits(k0, k1, p2) >> 9;
    bool e1 = (eb[p1 >> 6] >> (p1 & 63)) & 1ull;
    bool e2 = (eb[p2 >> 6] >> (p2 & 63)) & 1ull;
    if (e1 && v1 >= T) {
      uint32_t pos = atomicAdd(&lcnt, 1u);
      uint64_t key = (((uint64_t)((~v1) & 0x7FFFFFu)) << 18) | p1;
      if (pos < (uint32_t)LBUF) lbuf[pos] = key;
      else { uint32_t gp = atomicAdd(&cnt[b], 1u);
             if (gp < (uint32_t)CAP2) list[(size_t)b * CAP2 + gp] = key; }
    }
    if (e2 && v2 >= T) {
      uint32_t pos = atomicAdd(&lcnt, 1u);
      uint64_t key = (((uint64_t)((~v2) & 0x7FFFFFu)) << 18) | p2;
      if (pos < (uint32_t)LBUF) lbuf[pos] = key;
      else { uint32_t gp = atomicAdd(&cnt[b], 1u);
             if (gp < (uint32_t)CAP2) list[(size_t)b * CAP2 + gp] = key; }
    }
  }
  __syncthreads();
  int m = min((int)lcnt, LBUF);
  if (t == 0) gbase = atomicAdd(&cnt[b], (uint32_t)m);
  __syncthreads();
  uint32_t base = gbase;
  for (int i = t; i < m; i += 1024) {
    uint32_t pos = base + (uint32_t)i;
    if (pos < (uint32_t)CAP2) list[(size_t)b * CAP2 + pos] = lbuf[i];
  }
}

// ---- exact in-block top-NSEED over candidate list (fg path) ----
__global__ __launch_bounds__(1024) void k_cut2xl(const uint32_t* __restrict__ Ea,
                                                 const uint32_t* __restrict__ cnt,
                                                 const uint64_t* __restrict__ list,
                                                 uint64_t* __restrict__ bm) {
  __shared__ uint32_t h[4096];
  __shared__ uint32_t S[256];
  __shared__ uint32_t sb2, sr2;
  __shared__ uint64_t tie[1024];
  __shared__ uint32_t tcnt;
  int b = blockIdx.x, t = threadIdx.x;
  if (Ea[b] <= (uint32_t)NSEED) return;
  int n = min((int)cnt[b], CAP2);
  if (n == 0) return;
  uint32_t target = (uint32_t)min(NSEED, n);
  const uint64_t* lb = list + (size_t)b * CAP2;
  uint64_t K0 = (t < n)        ? lb[t]        : 0;
  uint64_t K1 = (t + 1024 < n) ? lb[t + 1024] : 0;
  uint64_t K2 = (t + 2048 < n) ? lb[t + 2048] : 0;
  uint64_t K3 = (t + 3072 < n) ? lb[t + 3072] : 0;
  for (int i = t; i < 4096; i += 1024) h[i] = 0;
  if (t == 0) tcnt = 0;
  __syncthreads();
  if (t < n)        atomicAdd(&h[(uint32_t)(K0 >> 29)], 1u);
  if (t + 1024 < n) atomicAdd(&h[(uint32_t)(K1 >> 29)], 1u);
  if (t + 2048 < n) atomicAdd(&h[(uint32_t)(K2 >> 29)], 1u);
  if (t + 3072 < n) atomicAdd(&h[(uint32_t)(K3 >> 29)], 1u);
  __syncthreads();
  if (t < 256) {
    uint32_t s = 0;
#pragma unroll
    for (int i = 0; i < 16; ++i) s += h[t * 16 + i];
    S[t] = s;
  }
  __syncthreads();
  for (int st = 1; st < 256; st <<= 1) {
    uint32_t v = 0;
    if (t < 256 && t >= st) v = S[t - st];
    __syncthreads();
    if (t < 256) S[t] += v;
    __syncthreads();
  }
  if (t < 256) {
    uint32_t before = (t == 0) ? 0u : S[t - 1];
    if (S[t] >= target && before < target) {
      uint32_t acc = before;
      for (int i = 0; i < 16; ++i) {
        uint32_t c = h[t * 16 + i];
        if (acc + c >= target) { sb2 = (uint32_t)(t * 16 + i); sr2 = target - acc; break; }
        acc += c;
      }
    }
  }
  __syncthreads();
  uint32_t b2 = sb2, r2 = sr2;
#define PROC(KK, VALID) \
  if (VALID) { \
    uint32_t bin = (uint32_t)((KK) >> 29); \
    if (bin < b2) { \
      uint32_t p = (uint32_t)(KK) & 0x3FFFFu; \
      atomicOr((unsigned long long*)&bm[(size_t)b * WPI + (p >> 6)], 1ull << (p & 63)); \
    } else if (bin == b2) { \
      uint32_t pos = atomicAdd(&tcnt, 1u); \
      if (pos < 1024u) tie[pos] = (KK); \
    } \
  }
  PROC(K0, t < n) PROC(K1, t + 1024 < n) PROC(K2, t + 2048 < n) PROC(K3, t + 3072 < n)
#undef PROC
  __syncthreads();
  int m = min((int)tcnt, 1024);
  int r = min((int)r2, m);
  if (t < m) {
    uint64_t mk = tie[t];
    int rank = 0;
    for (int i = 0; i < m; ++i) rank += (tie[i] < mk) ? 1 : 0;
    if (rank < r) {
      uint32_t p = (uint32_t)mk & 0x3FFFFu;
      atomicOr((unsigned long long*)&bm[(size_t)b * WPI + (p >> 6)], 1ull << (p & 63));
    }
  }
}

// -------- fused 3x3 dilation + overlap removal + compose (4 px/thread) --------
__global__ __launch_bounds__(256) void k_compose4(const uint64_t* __restrict__ F,
                                                  const uint64_t* __restrict__ G,
                                                  int* __restrict__ out) {
  int tid = blockIdx.x * 256 + threadIdx.x;   // BATCH*HW/4 threads
  int w = tid >> 4;                           // global word index
  int sub = tid & 15;                         // 4-pixel group within word
  int iw = w & (WPI - 1);
  int r = iw >> 3, c = iw & 7;
  int ib = w - iw;                            // image word base
  uint64_t Fd = 0, Bd = 0;
#pragma unroll
  for (int dr = -1; dr <= 1; ++dr) {
    int rr = r + dr;
    if (rr < 0 || rr >= H) continue;
    int wi = ib + rr * 8 + c;
    uint64_t cf = F[wi], cg = G[wi];
    uint64_t lf = (c > 0) ? F[wi - 1] : 0ull, lg = (c > 0) ? G[wi - 1] : 0ull;
    uint64_t rf = (c < 7) ? F[wi + 1] : 0ull, rg = (c < 7) ? G[wi + 1] : 0ull;
    Fd |= cf | (cf << 1) | (lf >> 63) | (cf >> 1) | (rf << 63);
    Bd |= cg | (cg << 1) | (lg >> 63) | (cg >> 1) | (rg << 63);
  }
  uint64_t ov = Fd & Bd;
  Fd &= ~ov; Bd &= ~ov;
  int sh = sub * 4;
  int4 o;
  o.x = ((Fd >> (sh + 0)) & 1ull) ? 1 : (((Bd >> (sh + 0)) & 1ull) ? 0 : -255);
  o.y = ((Fd >> (sh + 1)) & 1ull) ? 1 : (((Bd >> (sh + 1)) & 1ull) ? 0 : -255);
  o.z = ((Fd >> (sh + 2)) & 1ull) ? 1 : (((Bd >> (sh + 2)) & 1ull) ? 0 : -255);
  o.w = ((Fd >> (sh + 3)) & 1ull) ? 1 : (((Bd >> (sh + 3)) & 1ull) ? 0 : -255);
  ((int4*)out)[tid] = o;
}

extern "C" void kernel_launch(void* const* d_in, const int* in_sizes, int n_in,
                              void* d_out, int out_size, void* d_ws, size_t ws_size,
                              hipStream_t stream) {
  (void)in_sizes; (void)n_in; (void)out_size; (void)ws_size;
  const float* x = (const float*)d_in[0];
  int* out = (int*)d_out;
  char* ws = (char*)d_ws;

  // g (u16 bins, 64 MB) lives in the OUTPUT buffer (128 MB): written by
  // k_binify, read only by k_main, fully overwritten by k_compose4 at the end.
  u16* g = (u16*)d_out;

  // ---- workspace layout ----
  uint32_t* keys = (uint32_t*)(ws + 0);       // 2048
  uint32_t* kbg  = (uint32_t*)(ws + 2048);    // 512
  int*      th   = (int*)     (ws + 2560);    // 512
  uint32_t* b1be = (uint32_t*)(ws + 3072);
  uint32_t* r1be = (uint32_t*)(ws + 3584);
  uint32_t* Tbg  = (uint32_t*)(ws + 4096);
  // zeroed region
  char* Z = ws + 8192;
  uint32_t* Efg    = (uint32_t*)(Z + 0);
  uint32_t* cnt_fg = (uint32_t*)(Z + 512);
  uint32_t* cnt_be = (uint32_t*)(Z + 1024);
  uint32_t* cnt_bg = (uint32_t*)(Z + 1536);
  uint32_t* gh     = (uint32_t*)(Z + 2048);             // 2 MB (4096*4*128)
  uint64_t* bmG    = (uint64_t*)(Z + 2048 + 2097152);   // 4 MB, bg select out
  size_t Zsize = 2048 + 2097152 + 4194304;              // ~6.3 MB
  char* P = Z + Zsize;
  uint64_t* list    = (uint64_t*)(P + 0);               // 4 MB (bg then fg candidates)
  uint64_t* list_be = (uint64_t*)(P + 4194304);         // 1 MB (bg ties)
  uint64_t* bmE     = (uint64_t*)(P + 5242880);         // 4 MB eroded ROI
  uint64_t* bmF     = (uint64_t*)(P + 9437184);         // 4 MB fg select out

  hipMemsetAsync(Z, 0, Zsize, stream);
  k_binify   <<<BATCH * 4, 1024, 0, stream>>>((const float4*)x, g, gh, keys, kbg, Tbg);
  k_otsu_scan<<<BATCH * 2, 256, 0, stream>>>(gh, kbg, th, b1be, r1be);
  k_main     <<<BATCH * 4, 1024, 0, stream>>>(g, x, th, b1be, Tbg, keys,
                                              Efg, cnt_bg, list, cnt_be, list_be, bmE);
  k_bgsel    <<<BATCH, 1024, 0, stream>>>(r1be, cnt_be, list_be, Tbg, keys,
                                          cnt_bg, list, bmG);
  k_selfg    <<<BATCH * 4, 1024, 0, stream>>>(bmE, keys, Efg, cnt_fg, list, bmF);
  k_cut2xl   <<<BATCH, 1024, 0, stream>>>(Efg, cnt_fg, list, bmF);
  k_compose4 <<<(BATCH * HW / 4) / 256, 256, 0, stream>>>(bmF, bmG, out);
}

// Round 2
// 388.843 us; speedup vs baseline: 1.1345x; 1.0700x over previous
//
#include <hip/hip_runtime.h>
#include <cstdint>

typedef unsigned short u16;

constexpr int BATCH = 128;
constexpr int H = 512, W = 512;
constexpr int HW = H * W;       // 2^18
constexpr int WPR = W / 64;     // 8 words per row
constexpr int WPI = HW / 64;    // 4096 words per image
constexpr int NSEED = 1000;
constexpr int MARGIN = 3000;    // expected candidate count for threshold select
constexpr int CAP2 = 4096;      // per-image candidate list capacity
constexpr int CAPS = 1024;      // tie list capacity (mean ~64)
constexpr int LBUF = 2048;      // per-block LDS candidate buffer
constexpr int NBIN = 4096;      // gh stride; bins 0..4079 used (g = floor(v*4080))
constexpr int QSEG = 576;       // per-wave eligible ring (row adds <=512, carry <64)

// ---------------- Threefry-2x32 (20 rounds), bit-exact vs JAX ----------------
__device__ __forceinline__ uint32_t rotl32(uint32_t v, int d) {
  return (v << d) | (v >> (32 - d));
}

__device__ __forceinline__ void tf2x32(uint32_t k0, uint32_t k1,
                                       uint32_t x0, uint32_t x1,
                                       uint32_t &o0, uint32_t &o1) {
  uint32_t ks2 = k0 ^ k1 ^ 0x1BD11BDAu;
  x0 += k0; x1 += k1;
  x0 += x1; x1 = rotl32(x1, 13); x1 ^= x0;
  x0 += x1; x1 = rotl32(x1, 15); x1 ^= x0;
  x0 += x1; x1 = rotl32(x1, 26); x1 ^= x0;
  x0 += x1; x1 = rotl32(x1, 6);  x1 ^= x0;
  x0 += k1; x1 += ks2 + 1u;
  x0 += x1; x1 = rotl32(x1, 17); x1 ^= x0;
  x0 += x1; x1 = rotl32(x1, 29); x1 ^= x0;
  x0 += x1; x1 = rotl32(x1, 16); x1 ^= x0;
  x0 += x1; x1 = rotl32(x1, 24); x1 ^= x0;
  x0 += ks2; x1 += k0 + 2u;
  x0 += x1; x1 = rotl32(x1, 13); x1 ^= x0;
  x0 += x1; x1 = rotl32(x1, 15); x1 ^= x0;
  x0 += x1; x1 = rotl32(x1, 26); x1 ^= x0;
  x0 += x1; x1 = rotl32(x1, 6);  x1 ^= x0;
  x0 += k0; x1 += k1 + 3u;
  x0 += x1; x1 = rotl32(x1, 17); x1 ^= x0;
  x0 += x1; x1 = rotl32(x1, 29); x1 ^= x0;
  x0 += x1; x1 = rotl32(x1, 16); x1 ^= x0;
  x0 += x1; x1 = rotl32(x1, 24); x1 ^= x0;
  x0 += k1; x1 += ks2 + 4u;
  x0 += x1; x1 = rotl32(x1, 13); x1 ^= x0;
  x0 += x1; x1 = rotl32(x1, 15); x1 ^= x0;
  x0 += x1; x1 = rotl32(x1, 26); x1 ^= x0;
  x0 += x1; x1 = rotl32(x1, 6);  x1 ^= x0;
  x0 += ks2; x1 += k0 + 5u;
  o0 = x0; o1 = x1;
}

__device__ __forceinline__ uint32_t score_bits(uint32_t k0, uint32_t k1, uint32_t i) {
  uint32_t a, c; tf2x32(k0, k1, 0u, i, a, c);
  return a ^ c;
}

// ---------------- per-image keys + nbr_bg + bg score threshold ----------------
__device__ __forceinline__ void keygen(int b, uint32_t* keys, uint32_t* kbg,
                                       uint32_t* Tbg) {
  uint32_t kb0, kb1; tf2x32(0u, 42u, 0u, (uint32_t)b, kb0, kb1);
  uint32_t kf0, kf1; tf2x32(kb0, kb1, 0u, 0u, kf0, kf1);
  uint32_t kB0, kB1; tf2x32(kb0, kb1, 0u, 1u, kB0, kB1);
  uint32_t kz0, kz1; tf2x32(kb0, kb1, 0u, 2u, kz0, kz1);
  uint32_t za, zc; tf2x32(kz0, kz1, 0u, 0u, za, zc);
  uint32_t zb = za ^ zc;
  keys[b * 4 + 0] = kf0; keys[b * 4 + 1] = kf1;
  keys[b * 4 + 2] = kB0; keys[b * 4 + 3] = kB1;
  float uu = __uint_as_float((zb >> 9) | 0x3f800000u) - 1.0f;
  float span = __fsub_rn(0.7f, 0.3f);
  float z = __fadd_rn(__fmul_rn(uu, span), 0.3f);
  z = fmaxf(0.3f, z);
  float nb = ceilf(__fmul_rn(z, (float)HW));
  uint32_t K = (uint32_t)nb;
  kbg[b] = K;
  float tv = floorf((1.0f - (float)MARGIN / (float)K) * 8388608.0f);
  Tbg[b] = (uint32_t)fmaxf(tv, 0.0f);
}

// -------- fused x sweep: per-sub 4080-bin hist (pure stores) + u16 bins +
//          keygen + counter zeroing (replaces host memset) --------
__global__ __launch_bounds__(1024) void k_binify(const float4* __restrict__ x4,
                                                 u16* __restrict__ g,
                                                 uint32_t* __restrict__ gh,
                                                 uint32_t* __restrict__ keys,
                                                 uint32_t* __restrict__ kbg,
                                                 uint32_t* __restrict__ Tbg,
                                                 uint32_t* __restrict__ Efg,
                                                 uint32_t* __restrict__ cnt_fg,
                                                 uint32_t* __restrict__ cnt_be,
                                                 uint32_t* __restrict__ cnt_bg) {
  __shared__ uint32_t h[NBIN];
  int b = blockIdx.x >> 2, sub = blockIdx.x & 3, t = threadIdx.x;
  if (blockIdx.x == 0 && t < BATCH) {
    keygen(t, keys, kbg, Tbg);
    Efg[t] = 0; cnt_fg[t] = 0; cnt_be[t] = 0; cnt_bg[t] = 0;
  }
  for (int i = t; i < NBIN; i += 1024) h[i] = 0;
  __syncthreads();
  const float4* xb = x4 + ((size_t)b * HW + (size_t)sub * (HW / 4)) / 4;
  ushort4* gb4 = (ushort4*)g + ((size_t)b * HW + (size_t)sub * (HW / 4)) / 4;
  for (int i = t; i < HW / 16; i += 1024) {
    float4 v4 = xb[i];
    int g0 = (int)floorf(__fmul_rn(v4.x, 4080.0f)); g0 = min(max(g0, 0), 4079);
    int g1 = (int)floorf(__fmul_rn(v4.y, 4080.0f)); g1 = min(max(g1, 0), 4079);
    int g2 = (int)floorf(__fmul_rn(v4.z, 4080.0f)); g2 = min(max(g2, 0), 4079);
    int g3 = (int)floorf(__fmul_rn(v4.w, 4080.0f)); g3 = min(max(g3, 0), 4079);
    atomicAdd(&h[g0], 1u);
    atomicAdd(&h[g1], 1u);
    atomicAdd(&h[g2], 1u);
    atomicAdd(&h[g3], 1u);
    ushort4 o;
    o.x = (u16)g0; o.y = (u16)g1; o.z = (u16)g2; o.w = (u16)g3;
    gb4[i] = o;
  }
  __syncthreads();
  uint32_t* dst = gh + ((size_t)blockIdx.x << 12);   // per-(b,sub) histogram
  for (int i = t; i < NBIN; i += 1024) dst[i] = h[i];
}

// ------- fused Otsu (blocks 0..127, h256 from gh group-sums) + K-scan -------
__device__ __forceinline__ void lds_tree_cumsum256(float* L, float* S, int tid) {
  const int off[9] = {0, 256, 384, 448, 480, 496, 504, 508, 510};
  const int sz[9]  = {256, 128, 64, 32, 16, 8, 4, 2, 1};
  for (int l = 0; l < 8; ++l) {
    int o = off[l], on = off[l + 1], n = sz[l + 1];
    if (tid < n) L[on + tid] = __fadd_rn(L[o + 2 * tid], L[o + 2 * tid + 1]);
    __syncthreads();
  }
  if (tid == 0) S[off[8]] = L[off[8]];
  __syncthreads();
  for (int l = 7; l >= 0; --l) {
    int o = off[l], on = off[l + 1], hn = sz[l] / 2;
    if (tid == 0) S[o] = L[o];
    if (tid < hn) S[o + 2 * tid + 1] = S[on + tid];
    if (tid >= 1 && tid < hn) S[o + 2 * tid] = __fadd_rn(S[on + tid - 1], L[o + 2 * tid]);
    __syncthreads();
  }
}

__global__ __launch_bounds__(256) void k_otsu_scan(const uint32_t* __restrict__ gh,
                                                   const uint32_t* __restrict__ Ka,
                                                   int* __restrict__ th_out,
                                                   uint32_t* __restrict__ b1a,
                                                   uint32_t* __restrict__ r1a) {
  __shared__ float L[511], S[511], wc[256], mm[256];
  __shared__ float sv[256];
  __shared__ int si[256];
  __shared__ uint32_t h[NBIN];
  __shared__ uint32_t ps[256];
  int tid = threadIdx.x;
  int b = (blockIdx.x < BATCH) ? blockIdx.x : (blockIdx.x - BATCH);
  const uint32_t* g0 = gh + ((size_t)(b * 4 + 0) << 12);
  const uint32_t* g1 = gh + ((size_t)(b * 4 + 1) << 12);
  const uint32_t* g2 = gh + ((size_t)(b * 4 + 2) << 12);
  const uint32_t* g3 = gh + ((size_t)(b * 4 + 3) << 12);
  for (int i = tid; i < NBIN; i += 256) h[i] = g0[i] + g1[i] + g2[i] + g3[i];
  __syncthreads();
  if (blockIdx.x < BATCH) {
    uint32_t hv = 0;
#pragma unroll
    for (int i = 0; i < 16; ++i) hv += h[tid * 16 + i];   // h256[tid], exact
    L[tid] = (float)hv;
    __syncthreads();
    lds_tree_cumsum256(L, S, tid);
    wc[tid] = S[tid];
    __syncthreads();
    L[tid] = __fmul_rn((float)hv, (float)tid);
    __syncthreads();
    lds_tree_cumsum256(L, S, tid);
    mm[tid] = S[tid];
    __syncthreads();
    float total = (float)HW;
    float mT = mm[255];
    {
      float w = wc[tid];
      float denom = __fmul_rn(w, __fsub_rn(total, w));
      float s = 0.0f;
      if (denom > 0.0f) {
        float d  = __fsub_rn(__fmul_rn(mT, w), __fmul_rn(total, mm[tid]));
        float nu = __fmul_rn(d, d);
        float dd = __fmul_rn(__fmul_rn(denom, total), total);
        s = __fdiv_rn(nu, dd);
      }
      sv[tid] = s; si[tid] = tid;
    }
    __syncthreads();
    for (int st = 128; st >= 1; st >>= 1) {
      if (tid < st) {
        float s2 = sv[tid + st]; int i2 = si[tid + st];
        if (s2 > sv[tid] || (s2 == sv[tid] && i2 < si[tid])) { sv[tid] = s2; si[tid] = i2; }
      }
      __syncthreads();
    }
    if (tid == 0) {
      int bi = si[0];
      if (bi == 0) bi = 1;
      if (bi == 255) bi = 254;
      th_out[b] = bi;
    }
  } else {
    uint32_t K = Ka[b];
    uint32_t s = 0;
#pragma unroll
    for (int i = 0; i < 16; ++i) s += h[tid * 16 + i];
    ps[tid] = s;
    __syncthreads();
    if (tid == 0) {
      uint32_t acc = 0, b1 = 0, r1 = 1;
      for (int c = 0; c < 256; ++c) {
        if (acc + ps[c] >= K) {
          for (int bin = c * 16; bin < c * 16 + 16; ++bin) {
            uint32_t cc = h[bin];
            if (acc + cc >= K) { b1 = (uint32_t)bin; r1 = K - acc; break; }
            acc += cc;
          }
          break;
        }
        acc += ps[c];
      }
      b1a[b] = b1; r1a[b] = r1;
    }
  }
}

// ==== mega-fused: ROI bits + 11x11 erosion + E count + bg candidates.
//      Barrier-free phase A: per-wave eligible ring + inline wave drains.
__global__ __launch_bounds__(1024) void k_main(const u16* __restrict__ gq,
                                               const float* __restrict__ x,
                                               const int* __restrict__ th,
                                               const uint32_t* __restrict__ b1a,
                                               const uint32_t* __restrict__ Tbg,
                                               const uint32_t* __restrict__ keys,
                                               uint32_t* __restrict__ Efg,
                                               uint32_t* __restrict__ cnt_bg,
                                               uint64_t* __restrict__ list,
                                               uint32_t* __restrict__ cnt_be,
                                               uint64_t* __restrict__ list_be,
                                               uint64_t* __restrict__ erod) {
  __shared__ uint64_t sroi[1104];      // roi bits, slab rows (<=138) x 8 words
  __shared__ uint64_t srow[1104];      // after 11-wide row min
  __shared__ uint32_t wq[16 * QSEG];   // per-wave eligible rings
  __shared__ uint64_t lbuf[LBUF];      // candidate keys
  __shared__ uint32_t lcnt, gbase;
  int b = blockIdx.x >> 2, sub = blockIdx.x & 3, t = threadIdx.x;
  int wave = t >> 6, lane = t & 63;
  int R0 = sub * 128;
  int rlo = max(R0 - 5, 0), rhi = min(R0 + 133, H);
  int nwords = (rhi - rlo) * 8;
  const u16* gb = gq + (size_t)b * HW;
  const float* xb = x + (size_t)b * HW;
  int groi = (th[b] + 1) << 4;     // g >= 16*(th+1)  <=>  floor(v*255) > th
  uint32_t b1 = b1a[b];
  uint32_t T = Tbg[b];
  uint32_t k0 = keys[b * 4 + 2], k1 = keys[b * 4 + 3];
  if (t == 0) lcnt = 0;
  __syncthreads();
  uint32_t* q = wq + wave * QSEG;
  uint32_t qlen = 0, hd = 0;
  uint64_t lmask = (1ull << lane) - 1ull;
  // phase A: wave owns 8 core rows; ballot + ring append; drain 64 at a time
  for (int r = 0; r < 8; ++r) {
    int absr = R0 + wave * 8 + r;
    int rowbase = absr * W + lane;
    int swbase = (absr - rlo) * 8;
    const u16* gp8 = gb + rowbase;
    u16 gvals[8];
#pragma unroll
    for (int c = 0; c < 8; ++c) gvals[c] = gp8[c * 64];
#pragma unroll
    for (int c = 0; c < 8; ++c) {
      uint32_t gv = (uint32_t)gvals[c];
      uint64_t bw = __ballot((int)gv >= groi);
      if (lane == 0) sroi[swbase + c] = bw;
      bool elig = gv < b1;
      uint64_t m = __ballot(elig);
      if (elig) {
        uint32_t rank = (uint32_t)__popcll(m & lmask);
        uint32_t idx = hd + qlen + rank;
        if (idx >= (uint32_t)QSEG) idx -= (uint32_t)QSEG;
        q[idx] = (uint32_t)(rowbase + c * 64);
      }
      qlen += (uint32_t)__popcll(m);
      if (gv == b1) {   // rare (~64/image): boundary bin, exact-value tie
        uint32_t gp = atomicAdd(&cnt_be[b], 1u);
        if (gp < (uint32_t)CAPS)
          list_be[(size_t)b * CAPS + gp] =
              (((uint64_t)__float_as_uint(xb[rowbase + c * 64])) << 18) |
              (uint32_t)(rowbase + c * 64);
      }
    }
    while (qlen >= 64u) {            // wave-uniform; no block barrier
      __builtin_amdgcn_wave_barrier();
      uint32_t idx = hd + (uint32_t)lane;
      if (idx >= (uint32_t)QSEG) idx -= (uint32_t)QSEG;
      uint32_t p = q[idx];
      hd += 64u; if (hd >= (uint32_t)QSEG) hd -= (uint32_t)QSEG;
      qlen -= 64u;
      uint32_t v = score_bits(k0, k1, p) >> 9;
      if (v >= T) {
        uint32_t pos = atomicAdd(&lcnt, 1u);
        uint64_t key = (((uint64_t)((~v) & 0x7FFFFFu)) << 18) | p;
        if (pos < (uint32_t)LBUF) lbuf[pos] = key;
        else { uint32_t gp = atomicAdd(&cnt_bg[b], 1u);
               if (gp < (uint32_t)CAP2) list[(size_t)b * CAP2 + gp] = key; }
      }
    }
  }
  if (qlen) {                        // tail (<64 entries)
    __builtin_amdgcn_wave_barrier();
    if ((uint32_t)lane < qlen) {
      uint32_t idx = hd + (uint32_t)lane;
      if (idx >= (uint32_t)QSEG) idx -= (uint32_t)QSEG;
      uint32_t p = q[idx];
      uint32_t v = score_bits(k0, k1, p) >> 9;
      if (v >= T) {
        uint32_t pos = atomicAdd(&lcnt, 1u);
        uint64_t key = (((uint64_t)((~v) & 0x7FFFFFu)) << 18) | p;
        if (pos < (uint32_t)LBUF) lbuf[pos] = key;
        else { uint32_t gp = atomicAdd(&cnt_bg[b], 1u);
               if (gp < (uint32_t)CAP2) list[(size_t)b * CAP2 + gp] = key; }
      }
    }
  }
  // halo rows: roi bits only
  {
    int lowWords = (R0 - rlo) * 8;
    int nh = nwords - 1024;
    for (int i = wave; i < nh; i += 16) {
      int wi = i + ((i < lowWords) ? 0 : 1024);
      int absr = rlo + (wi >> 3);
      int c = wi & 7;
      uint32_t gv = (uint32_t)gb[absr * W + c * 64 + lane];
      uint64_t bw = __ballot((int)gv >= groi);
      if (lane == 0) sroi[wi] = bw;
    }
  }
  __syncthreads();
  // 11-wide row min over slab
  for (int wi = t; wi < nwords; wi += 1024) {
    int c = wi & 7;
    uint64_t cur = sroi[wi];
    uint64_t left  = (c > 0) ? sroi[wi - 1] : ~0ull;
    uint64_t right = (c < 7) ? sroi[wi + 1] : ~0ull;
    uint64_t res = cur;
#pragma unroll
    for (int s = 1; s <= 5; ++s) {
      res &= (cur >> s) | (right << (64 - s));
      res &= (cur << s) | (left >> (64 - s));
    }
    srow[wi] = res;
  }
  __syncthreads();
  // 11-tall col min for core rows (exactly 1024 words) + popcount
  {
    int coreRow = t >> 3, c = t & 7;
    int absr = R0 + coreRow;
    int s = absr - rlo;
    uint64_t res = srow[s * 8 + c];
#pragma unroll
    for (int d = 1; d <= 5; ++d) {
      if (absr - d >= 0) res &= srow[(s - d) * 8 + c];
      if (absr + d < H)  res &= srow[(s + d) * 8 + c];
    }
    erod[(size_t)b * WPI + absr * 8 + c] = res;
    uint32_t pc = (uint32_t)__popcll(res);
    for (int sh = 32; sh >= 1; sh >>= 1) pc += __shfl_down(pc, sh);
    if (lane == 0 && pc) atomicAdd(&Efg[b], pc);
  }
  __syncthreads();
  // bulk candidate append
  int m = min((int)lcnt, LBUF);
  if (t == 0) gbase = atomicAdd(&cnt_bg[b], (uint32_t)m);
  __syncthreads();
  uint32_t base = gbase;
  for (int i = t; i < m; i += 1024) {
    uint32_t pos = base + (uint32_t)i;
    if (pos < (uint32_t)CAP2) list[(size_t)b * CAP2 + pos] = lbuf[i];
  }
}

// ---- merged select: blocks 0..127 bg (tie extras + exact top-NSEED -> bmG),
//      blocks 128..255 fg (whole-image sweep + top-NSEED -> bmF; no-op when
//      E<=NSEED since compose reads bmE directly). Zeroes its own bitmaps.
__global__ __launch_bounds__(1024) void k_select(const uint32_t* __restrict__ r1a,
                                                 const uint32_t* __restrict__ cnt_be,
                                                 const uint64_t* __restrict__ list_be,
                                                 const uint32_t* __restrict__ Tbg,
                                                 const uint32_t* __restrict__ keys,
                                                 const uint32_t* __restrict__ cnt_bg,
                                                 const uint64_t* __restrict__ list,
                                                 uint64_t* __restrict__ bmG,
                                                 const uint32_t* __restrict__ Ea,
                                                 uint32_t* __restrict__ cnt_fg,
                                                 uint64_t* __restrict__ list_fg,
                                                 const uint64_t* __restrict__ bmE,
                                                 uint64_t* __restrict__ bmF) {
  __shared__ uint64_t pool[5248];   // 41 KB, carved per role
  __shared__ uint32_t ecnt, tcnt, lcnt, gbase, sb2, sr2;
  int t = threadIdx.x;
  uint32_t* h = (uint32_t*)(pool + 2048);   // u32[4096]
  uint64_t* tie = pool + 4096;              // u64[1024]
  uint32_t* S = (uint32_t*)(pool + 5120);   // u32[256]
  if (blockIdx.x < BATCH) {
    // ---------------- bg path ----------------
    int b = blockIdx.x;
    uint64_t* ks = pool;            // u64[1024]
    uint64_t* ebuf = pool + 1024;   // u64[1024]
    uint64_t* bg = bmG + (size_t)b * WPI;
    for (int i = t; i < WPI; i += 1024) bg[i] = 0;   // replaces host memset
    int nbe = min((int)cnt_be[b], CAPS);
    if (t == 0) { ecnt = 0; tcnt = 0; }
    if (t < nbe) ks[t] = list_be[(size_t)b * CAPS + t];
    __syncthreads();
    if (t < nbe) {
      uint64_t mk = ks[t];
      int rank = 0;
      for (int i = 0; i < nbe; ++i) rank += (ks[i] < mk) ? 1 : 0;
      int r = min((int)r1a[b], nbe);
      if (rank < r) {
        uint32_t p = (uint32_t)(mk & 0x3FFFFull);
        uint32_t v = score_bits(keys[b * 4 + 2], keys[b * 4 + 3], p) >> 9;
        if (v >= Tbg[b]) {
          uint32_t slot = atomicAdd(&ecnt, 1u);
          ebuf[slot] = (((uint64_t)((~v) & 0x7FFFFFu)) << 18) | p;
        }
      }
    }
    for (int i = t; i < 4096; i += 1024) h[i] = 0;
    __syncthreads();
    int n0 = min((int)cnt_bg[b], CAP2);
    int ne = (int)ecnt;
    int n = n0 + ne;
    if (n == 0) return;
    uint32_t target = (uint32_t)min(NSEED, n);
    const uint64_t* lb = list + (size_t)b * CAP2;
    uint64_t K0 = (t < n0)        ? lb[t]        : 0;
    uint64_t K1 = (t + 1024 < n0) ? lb[t + 1024] : 0;
    uint64_t K2 = (t + 2048 < n0) ? lb[t + 2048] : 0;
    uint64_t K3 = (t + 3072 < n0) ? lb[t + 3072] : 0;
    uint64_t KE = (t < ne)        ? ebuf[t]      : 0;
    if (t < n0)        atomicAdd(&h[(uint32_t)(K0 >> 29)], 1u);
    if (t + 1024 < n0) atomicAdd(&h[(uint32_t)(K1 >> 29)], 1u);
    if (t + 2048 < n0) atomicAdd(&h[(uint32_t)(K2 >> 29)], 1u);
    if (t + 3072 < n0) atomicAdd(&h[(uint32_t)(K3 >> 29)], 1u);
    if (t < ne)        atomicAdd(&h[(uint32_t)(KE >> 29)], 1u);
    __syncthreads();
    if (t < 256) {
      uint32_t s = 0;
#pragma unroll
      for (int i = 0; i < 16; ++i) s += h[t * 16 + i];
      S[t] = s;
    }
    __syncthreads();
    for (int st = 1; st < 256; st <<= 1) {
      uint32_t v = 0;
      if (t < 256 && t >= st) v = S[t - st];
      __syncthreads();
      if (t < 256) S[t] += v;
      __syncthreads();
    }
    if (t < 256) {
      uint32_t before = (t == 0) ? 0u : S[t - 1];
      if (S[t] >= target && before < target) {
        uint32_t acc = before;
        for (int i = 0; i < 16; ++i) {
          uint32_t c = h[t * 16 + i];
          if (acc + c >= target) { sb2 = (uint32_t)(t * 16 + i); sr2 = target - acc; break; }
          acc += c;
        }
      }
    }
    __syncthreads();
    uint32_t b2 = sb2, r2 = sr2;
#define PROC(KK, VALID) \
    if (VALID) { \
      uint32_t bin = (uint32_t)((KK) >> 29); \
      if (bin < b2) { \
        uint32_t p = (uint32_t)(KK) & 0x3FFFFu; \
        atomicOr((unsigned long long*)&bg[p >> 6], 1ull << (p & 63)); \
      } else if (bin == b2) { \
        uint32_t pos = atomicAdd(&tcnt, 1u); \
        if (pos < 1024u) tie[pos] = (KK); \
      } \
    }
    PROC(K0, t < n0) PROC(K1, t + 1024 < n0) PROC(K2, t + 2048 < n0)
    PROC(K3, t + 3072 < n0) PROC(KE, t < ne)
#undef PROC
    __syncthreads();
    int m = min((int)tcnt, 1024);
    int r = min((int)r2, m);
    if (t < m) {
      uint64_t mk = tie[t];
      int rank = 0;
      for (int i = 0; i < m; ++i) rank += (tie[i] < mk) ? 1 : 0;
      if (rank < r) {
        uint32_t p = (uint32_t)mk & 0x3FFFFu;
        atomicOr((unsigned long long*)&bg[p >> 6], 1ull << (p & 63));
      }
    }
  } else {
    // ---------------- fg path ----------------
    int b = blockIdx.x - BATCH;
    uint32_t E = Ea[b];
    if (E <= (uint32_t)NSEED) return;   // compose reads bmE directly
    uint64_t* lbuf = pool;              // u64[2048]
    const uint64_t* eb = bmE + (size_t)b * WPI;
    uint64_t* ob = bmF + (size_t)b * WPI;
    for (int i = t; i < WPI; i += 1024) ob[i] = 0;
    if (t == 0) { lcnt = 0; tcnt = 0; }
    __syncthreads();
    float tvf = floorf((1.0f - (float)MARGIN / (float)E) * 8388608.0f);
    uint32_t T = (uint32_t)fmaxf(tvf, 0.0f);
    uint32_t k0 = keys[b * 4 + 0], k1 = keys[b * 4 + 1];
    int lane = t & 63;
    for (int k = 0; k < HW / 1024; ++k) {
      uint32_t p = (uint32_t)(k * 1024 + t);
      uint64_t wbits = eb[p >> 6];
      if ((wbits >> lane) & 1ull) {
        uint32_t v = score_bits(k0, k1, p) >> 9;
        if (v >= T) {
          uint32_t pos = atomicAdd(&lcnt, 1u);
          uint64_t key = (((uint64_t)((~v) & 0x7FFFFFu)) << 18) | p;
          if (pos < (uint32_t)LBUF) lbuf[pos] = key;
          else { uint32_t gp = atomicAdd(&cnt_fg[b], 1u);
                 if (gp < (uint32_t)CAP2) list_fg[(size_t)b * CAP2 + gp] = key; }
        }
      }
    }
    __syncthreads();
    int m2 = min((int)lcnt, LBUF);
    if (t == 0) gbase = atomicAdd(&cnt_fg[b], (uint32_t)m2);
    __syncthreads();
    for (int i = t; i < m2; i += 1024) {
      uint32_t pos = gbase + (uint32_t)i;
      if (pos < (uint32_t)CAP2) list_fg[(size_t)b * CAP2 + pos] = lbuf[i];
    }
    __syncthreads();
    // exact top-NSEED cut
    int n = min((int)cnt_fg[b], CAP2);
    if (n == 0) return;
    uint32_t target = (uint32_t)min(NSEED, n);
    const uint64_t* lb = list_fg + (size_t)b * CAP2;
    uint64_t K0 = (t < n)        ? lb[t]        : 0;
    uint64_t K1 = (t + 1024 < n) ? lb[t + 1024] : 0;
    uint64_t K2 = (t + 2048 < n) ? lb[t + 2048] : 0;
    uint64_t K3 = (t + 3072 < n) ? lb[t + 3072] : 0;
    for (int i = t; i < 4096; i += 1024) h[i] = 0;
    __syncthreads();
    if (t < n)        atomicAdd(&h[(uint32_t)(K0 >> 29)], 1u);
    if (t + 1024 < n) atomicAdd(&h[(uint32_t)(K1 >> 29)], 1u);
    if (t + 2048 < n) atomicAdd(&h[(uint32_t)(K2 >> 29)], 1u);
    if (t + 3072 < n) atomicAdd(&h[(uint32_t)(K3 >> 29)], 1u);
    __syncthreads();
    if (t < 256) {
      uint32_t s = 0;
#pragma unroll
      for (int i = 0; i < 16; ++i) s += h[t * 16 + i];
      S[t] = s;
    }
    __syncthreads();
    for (int st = 1; st < 256; st <<= 1) {
      uint32_t v = 0;
      if (t < 256 && t >= st) v = S[t - st];
      __syncthreads();
      if (t < 256) S[t] += v;
      __syncthreads();
    }
    if (t < 256) {
      uint32_t before = (t == 0) ? 0u : S[t - 1];
      if (S[t] >= target && before < target) {
        uint32_t acc = before;
        for (int i = 0; i < 16; ++i) {
          uint32_t c = h[t * 16 + i];
          if (acc + c >= target) { sb2 = (uint32_t)(t * 16 + i); sr2 = target - acc; break; }
          acc += c;
        }
      }
    }
    __syncthreads();
    uint32_t b2 = sb2, r2 = sr2;
#define PROC(KK, VALID) \
    if (VALID) { \
      uint32_t bin = (uint32_t)((KK) >> 29); \
      if (bin < b2) { \
        uint32_t p = (uint32_t)(KK) & 0x3FFFFu; \
        atomicOr((unsigned long long*)&ob[p >> 6], 1ull << (p & 63)); \
      } else if (bin == b2) { \
        uint32_t pos = atomicAdd(&tcnt, 1u); \
        if (pos < 1024u) tie[pos] = (KK); \
      } \
    }
    PROC(K0, t < n) PROC(K1, t + 1024 < n) PROC(K2, t + 2048 < n) PROC(K3, t + 3072 < n)
#undef PROC
    __syncthreads();
    int m = min((int)tcnt, 1024);
    int r = min((int)r2, m);
    if (t < m) {
      uint64_t mk = tie[t];
      int rank = 0;
      for (int i = 0; i < m; ++i) rank += (tie[i] < mk) ? 1 : 0;
      if (rank < r) {
        uint32_t p = (uint32_t)mk & 0x3FFFFu;
        atomicOr((unsigned long long*)&ob[p >> 6], 1ull << (p & 63));
      }
    }
  }
}

// -------- fused 3x3 dilation + overlap removal + compose (4 px/thread);
//          fg source = bmE when E<=NSEED (skip-copy), else bmF --------
__global__ __launch_bounds__(256) void k_compose4(const uint64_t* __restrict__ bmE,
                                                  const uint64_t* __restrict__ bmF,
                                                  const uint64_t* __restrict__ G,
                                                  const uint32_t* __restrict__ Ea,
                                                  int* __restrict__ out) {
  int tid = blockIdx.x * 256 + threadIdx.x;   // BATCH*HW/4 threads
  int w = tid >> 4;                           // global word index
  int sub = tid & 15;                         // 4-pixel group within word
  int iw = w & (WPI - 1);
  int b = w >> 12;                            // WPI = 2^12
  const uint64_t* F = (Ea[b] <= (uint32_t)NSEED) ? bmE : bmF;
  int r = iw >> 3, c = iw & 7;
  int ib = w - iw;                            // image word base
  uint64_t Fd = 0, Bd = 0;
#pragma unroll
  for (int dr = -1; dr <= 1; ++dr) {
    int rr = r + dr;
    if (rr < 0 || rr >= H) continue;
    int wi = ib + rr * 8 + c;
    uint64_t cf = F[wi], cg = G[wi];
    uint64_t lf = (c > 0) ? F[wi - 1] : 0ull, lg = (c > 0) ? G[wi - 1] : 0ull;
    uint64_t rf = (c < 7) ? F[wi + 1] : 0ull, rg = (c < 7) ? G[wi + 1] : 0ull;
    Fd |= cf | (cf << 1) | (lf >> 63) | (cf >> 1) | (rf << 63);
    Bd |= cg | (cg << 1) | (lg >> 63) | (cg >> 1) | (rg << 63);
  }
  uint64_t ov = Fd & Bd;
  Fd &= ~ov; Bd &= ~ov;
  int sh = sub * 4;
  int4 o;
  o.x = ((Fd >> (sh + 0)) & 1ull) ? 1 : (((Bd >> (sh + 0)) & 1ull) ? 0 : -255);
  o.y = ((Fd >> (sh + 1)) & 1ull) ? 1 : (((Bd >> (sh + 1)) & 1ull) ? 0 : -255);
  o.z = ((Fd >> (sh + 2)) & 1ull) ? 1 : (((Bd >> (sh + 2)) & 1ull) ? 0 : -255);
  o.w = ((Fd >> (sh + 3)) & 1ull) ? 1 : (((Bd >> (sh + 3)) & 1ull) ? 0 : -255);
  ((int4*)out)[tid] = o;
}

extern "C" void kernel_launch(void* const* d_in, const int* in_sizes, int n_in,
                              void* d_out, int out_size, void* d_ws, size_t ws_size,
                              hipStream_t stream) {
  (void)in_sizes; (void)n_in; (void)out_size; (void)ws_size;
  const float* x = (const float*)d_in[0];
  int* out = (int*)d_out;
  char* ws = (char*)d_ws;

  // g (u16 bins, 64 MB) lives in the OUTPUT buffer (128 MB): written by
  // k_binify, read only by k_main, fully overwritten by k_compose4 at the end.
  u16* g = (u16*)d_out;

  // ---- workspace layout (no host memset needed) ----
  uint32_t* keys   = (uint32_t*)(ws + 0);       // 2048
  uint32_t* kbg    = (uint32_t*)(ws + 2048);    // 512
  int*      th     = (int*)     (ws + 2560);    // 512
  uint32_t* b1be   = (uint32_t*)(ws + 3072);
  uint32_t* r1be   = (uint32_t*)(ws + 3584);
  uint32_t* Tbg    = (uint32_t*)(ws + 4096);
  uint32_t* Efg    = (uint32_t*)(ws + 4608);
  uint32_t* cnt_fg = (uint32_t*)(ws + 5120);
  uint32_t* cnt_be = (uint32_t*)(ws + 5632);
  uint32_t* cnt_bg = (uint32_t*)(ws + 6144);
  char* P = ws + 8192;
  uint32_t* gh      = (uint32_t*)(P);                   // 8 MB (128*4 sub-hists)
  uint64_t* bmG     = (uint64_t*)(P + 8396800 - 8192);  // offsets below
  // recompute cleanly:
  uint64_t* _bmG    = (uint64_t*)(ws + 8192 + 8388608);            // 4 MB
  uint64_t* list    = (uint64_t*)(ws + 8192 + 8388608 + 4194304);  // 4 MB (bg)
  uint64_t* list_be = (uint64_t*)(ws + 8192 + 8388608 + 8388608);  // 1 MB
  uint64_t* bmE     = (uint64_t*)(ws + 8192 + 8388608 + 9437184);  // 4 MB
  uint64_t* bmF     = (uint64_t*)(ws + 8192 + 8388608 + 13631488); // 4 MB
  uint64_t* list_fg = (uint64_t*)gh;   // gh dead after k_otsu_scan; reuse (4 MB)
  (void)bmG;

  k_binify   <<<BATCH * 4, 1024, 0, stream>>>((const float4*)x, g, gh, keys, kbg,
                                              Tbg, Efg, cnt_fg, cnt_be, cnt_bg);
  k_otsu_scan<<<BATCH * 2, 256, 0, stream>>>(gh, kbg, th, b1be, r1be);
  k_main     <<<BATCH * 4, 1024, 0, stream>>>(g, x, th, b1be, Tbg, keys,
                                              Efg, cnt_bg, list, cnt_be, list_be, bmE);
  k_select   <<<BATCH * 2, 1024, 0, stream>>>(r1be, cnt_be, list_be, Tbg, keys,
                                              cnt_bg, list, _bmG,
                                              Efg, cnt_fg, list_fg, bmE, bmF);
  k_compose4 <<<(BATCH * HW / 4) / 256, 256, 0, stream>>>(bmE, bmF, _bmG, Efg, out);
}

// Round 3
// 379.037 us; speedup vs baseline: 1.1639x; 1.0259x over previous
//
#include <hip/hip_runtime.h>
#include <cstdint>

typedef unsigned short u16;

constexpr int BATCH = 128;
constexpr int H = 512, W = 512;
constexpr int HW = H * W;       // 2^18
constexpr int WPR = W / 64;     // 8 words per row
constexpr int WPI = HW / 64;    // 4096 words per image
constexpr int NSEED = 1000;
constexpr int MARGIN = 3000;    // expected candidate count for threshold select
constexpr int CAP2 = 4096;      // per-image candidate list capacity
constexpr int CAPS = 1024;      // tie list capacity (mean ~64)
constexpr int LBUF = 2048;      // per-block LDS candidate buffer
constexpr int NBIN = 4096;      // gh stride; bins 0..4079 used (g = floor(v*4080))
constexpr int QSEG = 576;       // per-wave eligible ring (row adds <=512, carry <64)

// ---------------- Threefry-2x32 (20 rounds), bit-exact vs JAX ----------------
__device__ __forceinline__ uint32_t rotl32(uint32_t v, int d) {
  return (v << d) | (v >> (32 - d));
}

__device__ __forceinline__ void tf2x32(uint32_t k0, uint32_t k1,
                                       uint32_t x0, uint32_t x1,
                                       uint32_t &o0, uint32_t &o1) {
  uint32_t ks2 = k0 ^ k1 ^ 0x1BD11BDAu;
  x0 += k0; x1 += k1;
  x0 += x1; x1 = rotl32(x1, 13); x1 ^= x0;
  x0 += x1; x1 = rotl32(x1, 15); x1 ^= x0;
  x0 += x1; x1 = rotl32(x1, 26); x1 ^= x0;
  x0 += x1; x1 = rotl32(x1, 6);  x1 ^= x0;
  x0 += k1; x1 += ks2 + 1u;
  x0 += x1; x1 = rotl32(x1, 17); x1 ^= x0;
  x0 += x1; x1 = rotl32(x1, 29); x1 ^= x0;
  x0 += x1; x1 = rotl32(x1, 16); x1 ^= x0;
  x0 += x1; x1 = rotl32(x1, 24); x1 ^= x0;
  x0 += ks2; x1 += k0 + 2u;
  x0 += x1; x1 = rotl32(x1, 13); x1 ^= x0;
  x0 += x1; x1 = rotl32(x1, 15); x1 ^= x0;
  x0 += x1; x1 = rotl32(x1, 26); x1 ^= x0;
  x0 += x1; x1 = rotl32(x1, 6);  x1 ^= x0;
  x0 += k0; x1 += k1 + 3u;
  x0 += x1; x1 = rotl32(x1, 17); x1 ^= x0;
  x0 += x1; x1 = rotl32(x1, 29); x1 ^= x0;
  x0 += x1; x1 = rotl32(x1, 16); x1 ^= x0;
  x0 += x1; x1 = rotl32(x1, 24); x1 ^= x0;
  x0 += k1; x1 += ks2 + 4u;
  x0 += x1; x1 = rotl32(x1, 13); x1 ^= x0;
  x0 += x1; x1 = rotl32(x1, 15); x1 ^= x0;
  x0 += x1; x1 = rotl32(x1, 26); x1 ^= x0;
  x0 += x1; x1 = rotl32(x1, 6);  x1 ^= x0;
  x0 += ks2; x1 += k0 + 5u;
  o0 = x0; o1 = x1;
}

__device__ __forceinline__ uint32_t score_bits(uint32_t k0, uint32_t k1, uint32_t i) {
  uint32_t a, c; tf2x32(k0, k1, 0u, i, a, c);
  return a ^ c;
}

// ---------------- per-image keys + nbr_bg + bg score threshold ----------------
__device__ __forceinline__ void keygen(int b, uint32_t* keys, uint32_t* kbg,
                                       uint32_t* Tbg) {
  uint32_t kb0, kb1; tf2x32(0u, 42u, 0u, (uint32_t)b, kb0, kb1);
  uint32_t kf0, kf1; tf2x32(kb0, kb1, 0u, 0u, kf0, kf1);
  uint32_t kB0, kB1; tf2x32(kb0, kb1, 0u, 1u, kB0, kB1);
  uint32_t kz0, kz1; tf2x32(kb0, kb1, 0u, 2u, kz0, kz1);
  uint32_t za, zc; tf2x32(kz0, kz1, 0u, 0u, za, zc);
  uint32_t zb = za ^ zc;
  keys[b * 4 + 0] = kf0; keys[b * 4 + 1] = kf1;
  keys[b * 4 + 2] = kB0; keys[b * 4 + 3] = kB1;
  float uu = __uint_as_float((zb >> 9) | 0x3f800000u) - 1.0f;
  float span = __fsub_rn(0.7f, 0.3f);
  float z = __fadd_rn(__fmul_rn(uu, span), 0.3f);
  z = fmaxf(0.3f, z);
  float nb = ceilf(__fmul_rn(z, (float)HW));
  uint32_t K = (uint32_t)nb;
  kbg[b] = K;
  float tv = floorf((1.0f - (float)MARGIN / (float)K) * 8388608.0f);
  Tbg[b] = (uint32_t)fmaxf(tv, 0.0f);
}

// -------- fused x sweep: per-sub 4080-bin hist (pure stores) + u16 bins +
//          keygen + counter zeroing (replaces host memset) --------
__global__ __launch_bounds__(1024) void k_binify(const float4* __restrict__ x4,
                                                 u16* __restrict__ g,
                                                 uint32_t* __restrict__ gh,
                                                 uint32_t* __restrict__ keys,
                                                 uint32_t* __restrict__ kbg,
                                                 uint32_t* __restrict__ Tbg,
                                                 uint32_t* __restrict__ Efg,
                                                 uint32_t* __restrict__ cnt_fg,
                                                 uint32_t* __restrict__ cnt_be,
                                                 uint32_t* __restrict__ cnt_bg) {
  __shared__ uint32_t h[NBIN];
  int b = blockIdx.x >> 2, sub = blockIdx.x & 3, t = threadIdx.x;
  if (blockIdx.x == 0 && t < BATCH) {
    keygen(t, keys, kbg, Tbg);
    Efg[t] = 0; cnt_fg[t] = 0; cnt_be[t] = 0; cnt_bg[t] = 0;
  }
  for (int i = t; i < NBIN; i += 1024) h[i] = 0;
  __syncthreads();
  const float4* xb = x4 + ((size_t)b * HW + (size_t)sub * (HW / 4)) / 4;
  ushort4* gb4 = (ushort4*)g + ((size_t)b * HW + (size_t)sub * (HW / 4)) / 4;
  for (int i = t; i < HW / 16; i += 1024) {
    float4 v4 = xb[i];
    int g0 = (int)floorf(__fmul_rn(v4.x, 4080.0f)); g0 = min(max(g0, 0), 4079);
    int g1 = (int)floorf(__fmul_rn(v4.y, 4080.0f)); g1 = min(max(g1, 0), 4079);
    int g2 = (int)floorf(__fmul_rn(v4.z, 4080.0f)); g2 = min(max(g2, 0), 4079);
    int g3 = (int)floorf(__fmul_rn(v4.w, 4080.0f)); g3 = min(max(g3, 0), 4079);
    atomicAdd(&h[g0], 1u);
    atomicAdd(&h[g1], 1u);
    atomicAdd(&h[g2], 1u);
    atomicAdd(&h[g3], 1u);
    ushort4 o;
    o.x = (u16)g0; o.y = (u16)g1; o.z = (u16)g2; o.w = (u16)g3;
    gb4[i] = o;
  }
  __syncthreads();
  uint32_t* dst = gh + ((size_t)blockIdx.x << 12);   // per-(b,sub) histogram
  for (int i = t; i < NBIN; i += 1024) dst[i] = h[i];
}

// ---- Otsu helper (bit-exact float pipeline; callable with >=256 threads) ----
__device__ __forceinline__ void lds_tree_cumsum256(float* L, float* S, int tid) {
  const int off[9] = {0, 256, 384, 448, 480, 496, 504, 508, 510};
  const int sz[9]  = {256, 128, 64, 32, 16, 8, 4, 2, 1};
  for (int l = 0; l < 8; ++l) {
    int o = off[l], on = off[l + 1], n = sz[l + 1];
    if (tid < n) L[on + tid] = __fadd_rn(L[o + 2 * tid], L[o + 2 * tid + 1]);
    __syncthreads();
  }
  if (tid == 0) S[off[8]] = L[off[8]];
  __syncthreads();
  for (int l = 7; l >= 0; --l) {
    int o = off[l], on = off[l + 1], hn = sz[l] / 2;
    if (tid == 0) S[o] = L[o];
    if (tid < hn) S[o + 2 * tid + 1] = S[on + tid];
    if (tid >= 1 && tid < hn) S[o + 2 * tid] = __fadd_rn(S[on + tid - 1], L[o + 2 * tid]);
    __syncthreads();
  }
}

// ==== mega-fused: inline Otsu+K-scan prologue (per block, redundant x4, exact)
//      + ROI bits + 11x11 erosion + E count + bg candidates.
__global__ __launch_bounds__(1024) void k_main(const u16* __restrict__ gq,
                                               const float* __restrict__ x,
                                               const uint32_t* __restrict__ gh,
                                               const uint32_t* __restrict__ kbg,
                                               const uint32_t* __restrict__ Tbg,
                                               const uint32_t* __restrict__ keys,
                                               uint32_t* __restrict__ r1a,
                                               uint32_t* __restrict__ Efg,
                                               uint32_t* __restrict__ cnt_bg,
                                               uint64_t* __restrict__ list,
                                               uint32_t* __restrict__ cnt_be,
                                               uint64_t* __restrict__ list_be,
                                               uint64_t* __restrict__ erod) {
  __shared__ union {
    struct { uint64_t sroi[1104]; uint64_t srow[1104]; } m;   // phase A/B
    struct { uint32_t h[NBIN]; float L[511]; float S[511];    // prologue
             float wc[256]; float mm[256]; float sv[256];
             int si[256]; uint32_t ps[256]; } o;
  } u;
  __shared__ uint32_t wq[16 * QSEG];   // per-wave eligible rings
  __shared__ uint64_t lbuf[LBUF];      // candidate keys
  __shared__ uint32_t lcnt, gbase;
  __shared__ int thS;
  __shared__ uint32_t b1S;
  int b = blockIdx.x >> 2, sub = blockIdx.x & 3, t = threadIdx.x;
  int wave = t >> 6, lane = t & 63;

  // ---------- prologue: Otsu threshold + ascending-K scan (from gh) ----------
  {
    const uint32_t* g0 = gh + ((size_t)(b * 4 + 0) << 12);
    const uint32_t* g1 = gh + ((size_t)(b * 4 + 1) << 12);
    const uint32_t* g2 = gh + ((size_t)(b * 4 + 2) << 12);
    const uint32_t* g3 = gh + ((size_t)(b * 4 + 3) << 12);
    for (int i = t; i < NBIN; i += 1024) u.o.h[i] = g0[i] + g1[i] + g2[i] + g3[i];
    __syncthreads();
    uint32_t hv = 0;
    if (t < 256) {
#pragma unroll
      for (int i = 0; i < 16; ++i) hv += u.o.h[t * 16 + i];   // h256[t], exact
      u.o.L[t] = (float)hv;
    }
    __syncthreads();
    lds_tree_cumsum256(u.o.L, u.o.S, t);
    if (t < 256) u.o.wc[t] = u.o.S[t];
    __syncthreads();
    if (t < 256) u.o.L[t] = __fmul_rn((float)hv, (float)t);
    __syncthreads();
    lds_tree_cumsum256(u.o.L, u.o.S, t);
    if (t < 256) u.o.mm[t] = u.o.S[t];
    __syncthreads();
    if (t < 256) {
      float total = (float)HW;
      float mT = u.o.mm[255];
      float w = u.o.wc[t];
      float denom = __fmul_rn(w, __fsub_rn(total, w));
      float s = 0.0f;
      if (denom > 0.0f) {
        float d  = __fsub_rn(__fmul_rn(mT, w), __fmul_rn(total, u.o.mm[t]));
        float nu = __fmul_rn(d, d);
        float dd = __fmul_rn(__fmul_rn(denom, total), total);
        s = __fdiv_rn(nu, dd);
      }
      u.o.sv[t] = s; u.o.si[t] = t;
    }
    __syncthreads();
    for (int st = 128; st >= 1; st >>= 1) {
      if (t < st) {
        float s2 = u.o.sv[t + st]; int i2 = u.o.si[t + st];
        if (s2 > u.o.sv[t] || (s2 == u.o.sv[t] && i2 < u.o.si[t])) {
          u.o.sv[t] = s2; u.o.si[t] = i2;
        }
      }
      __syncthreads();
    }
    if (t < 256) {
      uint32_t s = 0;
#pragma unroll
      for (int i = 0; i < 16; ++i) s += u.o.h[t * 16 + i];
      u.o.ps[t] = s;
    }
    __syncthreads();
    if (t == 0) {
      int bi = u.o.si[0];
      if (bi == 0) bi = 1;
      if (bi == 255) bi = 254;
      thS = bi;
      uint32_t K = kbg[b];
      uint32_t acc = 0, b1 = 0, r1 = 1;
      for (int c = 0; c < 256; ++c) {
        if (acc + u.o.ps[c] >= K) {
          for (int bin = c * 16; bin < c * 16 + 16; ++bin) {
            uint32_t cc = u.o.h[bin];
            if (acc + cc >= K) { b1 = (uint32_t)bin; r1 = K - acc; break; }
            acc += cc;
          }
          break;
        }
        acc += u.o.ps[c];
      }
      b1S = b1;
      if (sub == 0) r1a[b] = r1;
      lcnt = 0;
    }
    __syncthreads();
  }

  int R0 = sub * 128;
  int rlo = max(R0 - 5, 0), rhi = min(R0 + 133, H);
  int nwords = (rhi - rlo) * 8;
  const u16* gb = gq + (size_t)b * HW;
  const float* xb = x + (size_t)b * HW;
  int groi = (thS + 1) << 4;     // g >= 16*(th+1)  <=>  floor(v*255) > th
  uint32_t b1 = b1S;
  uint32_t T = Tbg[b];
  uint32_t k0 = keys[b * 4 + 2], k1 = keys[b * 4 + 3];
  uint32_t* q = wq + wave * QSEG;
  uint32_t qlen = 0, hd = 0;
  uint64_t lmask = (1ull << lane) - 1ull;
  // phase A: wave owns 8 core rows; ballot + ring append; drain 64 at a time
  for (int r = 0; r < 8; ++r) {
    int absr = R0 + wave * 8 + r;
    int rowbase = absr * W + lane;
    int swbase = (absr - rlo) * 8;
    const u16* gp8 = gb + rowbase;
    u16 gvals[8];
#pragma unroll
    for (int c = 0; c < 8; ++c) gvals[c] = gp8[c * 64];
#pragma unroll
    for (int c = 0; c < 8; ++c) {
      uint32_t gv = (uint32_t)gvals[c];
      uint64_t bw = __ballot((int)gv >= groi);
      if (lane == 0) u.m.sroi[swbase + c] = bw;
      bool elig = gv < b1;
      uint64_t m = __ballot(elig);
      if (elig) {
        uint32_t rank = (uint32_t)__popcll(m & lmask);
        uint32_t idx = hd + qlen + rank;
        if (idx >= (uint32_t)QSEG) idx -= (uint32_t)QSEG;
        q[idx] = (uint32_t)(rowbase + c * 64);
      }
      qlen += (uint32_t)__popcll(m);
      if (gv == b1) {   // rare (~64/image): boundary bin, exact-value tie
        uint32_t gp = atomicAdd(&cnt_be[b], 1u);
        if (gp < (uint32_t)CAPS)
          list_be[(size_t)b * CAPS + gp] =
              (((uint64_t)__float_as_uint(xb[rowbase + c * 64])) << 18) |
              (uint32_t)(rowbase + c * 64);
      }
    }
    while (qlen >= 64u) {            // wave-uniform; no block barrier
      __builtin_amdgcn_wave_barrier();
      uint32_t idx = hd + (uint32_t)lane;
      if (idx >= (uint32_t)QSEG) idx -= (uint32_t)QSEG;
      uint32_t p = q[idx];
      hd += 64u; if (hd >= (uint32_t)QSEG) hd -= (uint32_t)QSEG;
      qlen -= 64u;
      uint32_t v = score_bits(k0, k1, p) >> 9;
      if (v >= T) {
        uint32_t pos = atomicAdd(&lcnt, 1u);
        uint64_t key = (((uint64_t)((~v) & 0x7FFFFFu)) << 18) | p;
        if (pos < (uint32_t)LBUF) lbuf[pos] = key;
        else { uint32_t gp = atomicAdd(&cnt_bg[b], 1u);
               if (gp < (uint32_t)CAP2) list[(size_t)b * CAP2 + gp] = key; }
      }
    }
  }
  if (qlen) {                        // tail (<64 entries)
    __builtin_amdgcn_wave_barrier();
    if ((uint32_t)lane < qlen) {
      uint32_t idx = hd + (uint32_t)lane;
      if (idx >= (uint32_t)QSEG) idx -= (uint32_t)QSEG;
      uint32_t p = q[idx];
      uint32_t v = score_bits(k0, k1, p) >> 9;
      if (v >= T) {
        uint32_t pos = atomicAdd(&lcnt, 1u);
        uint64_t key = (((uint64_t)((~v) & 0x7FFFFFu)) << 18) | p;
        if (pos < (uint32_t)LBUF) lbuf[pos] = key;
        else { uint32_t gp = atomicAdd(&cnt_bg[b], 1u);
               if (gp < (uint32_t)CAP2) list[(size_t)b * CAP2 + gp] = key; }
      }
    }
  }
  // halo rows: roi bits only
  {
    int lowWords = (R0 - rlo) * 8;
    int nh = nwords - 1024;
    for (int i = wave; i < nh; i += 16) {
      int wi = i + ((i < lowWords) ? 0 : 1024);
      int absr = rlo + (wi >> 3);
      int c = wi & 7;
      uint32_t gv = (uint32_t)gb[absr * W + c * 64 + lane];
      uint64_t bw = __ballot((int)gv >= groi);
      if (lane == 0) u.m.sroi[wi] = bw;
    }
  }
  __syncthreads();
  // 11-wide row min over slab
  for (int wi = t; wi < nwords; wi += 1024) {
    int c = wi & 7;
    uint64_t cur = u.m.sroi[wi];
    uint64_t left  = (c > 0) ? u.m.sroi[wi - 1] : ~0ull;
    uint64_t right = (c < 7) ? u.m.sroi[wi + 1] : ~0ull;
    uint64_t res = cur;
#pragma unroll
    for (int s = 1; s <= 5; ++s) {
      res &= (cur >> s) | (right << (64 - s));
      res &= (cur << s) | (left >> (64 - s));
    }
    u.m.srow[wi] = res;
  }
  __syncthreads();
  // 11-tall col min for core rows (exactly 1024 words) + popcount
  {
    int coreRow = t >> 3, c = t & 7;
    int absr = R0 + coreRow;
    int s = absr - rlo;
    uint64_t res = u.m.srow[s * 8 + c];
#pragma unroll
    for (int d = 1; d <= 5; ++d) {
      if (absr - d >= 0) res &= u.m.srow[(s - d) * 8 + c];
      if (absr + d < H)  res &= u.m.srow[(s + d) * 8 + c];
    }
    erod[(size_t)b * WPI + absr * 8 + c] = res;
    uint32_t pc = (uint32_t)__popcll(res);
    for (int sh = 32; sh >= 1; sh >>= 1) pc += __shfl_down(pc, sh);
    if (lane == 0 && pc) atomicAdd(&Efg[b], pc);
  }
  __syncthreads();
  // bulk candidate append
  int m = min((int)lcnt, LBUF);
  if (t == 0) gbase = atomicAdd(&cnt_bg[b], (uint32_t)m);
  __syncthreads();
  uint32_t base = gbase;
  for (int i = t; i < m; i += 1024) {
    uint32_t pos = base + (uint32_t)i;
    if (pos < (uint32_t)CAP2) list[(size_t)b * CAP2 + pos] = lbuf[i];
  }
}

// ---- merged select: blocks 0..127 bg (tie extras + exact top-NSEED -> bmG),
//      blocks 128..255 fg (whole-image sweep + top-NSEED -> bmF; no-op when
//      E<=NSEED since compose reads bmE directly). Zeroes its own bitmaps.
__global__ __launch_bounds__(1024) void k_select(const uint32_t* __restrict__ r1a,
                                                 const uint32_t* __restrict__ cnt_be,
                                                 const uint64_t* __restrict__ list_be,
                                                 const uint32_t* __restrict__ Tbg,
                                                 const uint32_t* __restrict__ keys,
                                                 const uint32_t* __restrict__ cnt_bg,
                                                 const uint64_t* __restrict__ list,
                                                 uint64_t* __restrict__ bmG,
                                                 const uint32_t* __restrict__ Ea,
                                                 uint32_t* __restrict__ cnt_fg,
                                                 uint64_t* __restrict__ list_fg,
                                                 const uint64_t* __restrict__ bmE,
                                                 uint64_t* __restrict__ bmF) {
  __shared__ uint64_t pool[5248];   // 41 KB, carved per role
  __shared__ uint32_t ecnt, tcnt, lcnt, gbase, sb2, sr2;
  int t = threadIdx.x;
  uint32_t* h = (uint32_t*)(pool + 2048);   // u32[4096]
  uint64_t* tie = pool + 4096;              // u64[1024]
  uint32_t* S = (uint32_t*)(pool + 5120);   // u32[256]
  if (blockIdx.x < BATCH) {
    // ---------------- bg path ----------------
    int b = blockIdx.x;
    uint64_t* ks = pool;            // u64[1024]
    uint64_t* ebuf = pool + 1024;   // u64[1024]
    uint64_t* bg = bmG + (size_t)b * WPI;
    for (int i = t; i < WPI; i += 1024) bg[i] = 0;   // replaces host memset
    int nbe = min((int)cnt_be[b], CAPS);
    if (t == 0) { ecnt = 0; tcnt = 0; }
    if (t < nbe) ks[t] = list_be[(size_t)b * CAPS + t];
    __syncthreads();
    if (t < nbe) {
      uint64_t mk = ks[t];
      int rank = 0;
      for (int i = 0; i < nbe; ++i) rank += (ks[i] < mk) ? 1 : 0;
      int r = min((int)r1a[b], nbe);
      if (rank < r) {
        uint32_t p = (uint32_t)(mk & 0x3FFFFull);
        uint32_t v = score_bits(keys[b * 4 + 2], keys[b * 4 + 3], p) >> 9;
        if (v >= Tbg[b]) {
          uint32_t slot = atomicAdd(&ecnt, 1u);
          ebuf[slot] = (((uint64_t)((~v) & 0x7FFFFFu)) << 18) | p;
        }
      }
    }
    for (int i = t; i < 4096; i += 1024) h[i] = 0;
    __syncthreads();
    int n0 = min((int)cnt_bg[b], CAP2);
    int ne = (int)ecnt;
    int n = n0 + ne;
    if (n == 0) return;
    uint32_t target = (uint32_t)min(NSEED, n);
    const uint64_t* lb = list + (size_t)b * CAP2;
    uint64_t K0 = (t < n0)        ? lb[t]        : 0;
    uint64_t K1 = (t + 1024 < n0) ? lb[t + 1024] : 0;
    uint64_t K2 = (t + 2048 < n0) ? lb[t + 2048] : 0;
    uint64_t K3 = (t + 3072 < n0) ? lb[t + 3072] : 0;
    uint64_t KE = (t < ne)        ? ebuf[t]      : 0;
    if (t < n0)        atomicAdd(&h[(uint32_t)(K0 >> 29)], 1u);
    if (t + 1024 < n0) atomicAdd(&h[(uint32_t)(K1 >> 29)], 1u);
    if (t + 2048 < n0) atomicAdd(&h[(uint32_t)(K2 >> 29)], 1u);
    if (t + 3072 < n0) atomicAdd(&h[(uint32_t)(K3 >> 29)], 1u);
    if (t < ne)        atomicAdd(&h[(uint32_t)(KE >> 29)], 1u);
    __syncthreads();
    if (t < 256) {
      uint32_t s = 0;
#pragma unroll
      for (int i = 0; i < 16; ++i) s += h[t * 16 + i];
      S[t] = s;
    }
    __syncthreads();
    for (int st = 1; st < 256; st <<= 1) {
      uint32_t v = 0;
      if (t < 256 && t >= st) v = S[t - st];
      __syncthreads();
      if (t < 256) S[t] += v;
      __syncthreads();
    }
    if (t < 256) {
      uint32_t before = (t == 0) ? 0u : S[t - 1];
      if (S[t] >= target && before < target) {
        uint32_t acc = before;
        for (int i = 0; i < 16; ++i) {
          uint32_t c = h[t * 16 + i];
          if (acc + c >= target) { sb2 = (uint32_t)(t * 16 + i); sr2 = target - acc; break; }
          acc += c;
        }
      }
    }
    __syncthreads();
    uint32_t b2 = sb2, r2 = sr2;
#define PROC(KK, VALID) \
    if (VALID) { \
      uint32_t bin = (uint32_t)((KK) >> 29); \
      if (bin < b2) { \
        uint32_t p = (uint32_t)(KK) & 0x3FFFFu; \
        atomicOr((unsigned long long*)&bg[p >> 6], 1ull << (p & 63)); \
      } else if (bin == b2) { \
        uint32_t pos = atomicAdd(&tcnt, 1u); \
        if (pos < 1024u) tie[pos] = (KK); \
      } \
    }
    PROC(K0, t < n0) PROC(K1, t + 1024 < n0) PROC(K2, t + 2048 < n0)
    PROC(K3, t + 3072 < n0) PROC(KE, t < ne)
#undef PROC
    __syncthreads();
    int m = min((int)tcnt, 1024);
    int r = min((int)r2, m);
    if (t < m) {
      uint64_t mk = tie[t];
      int rank = 0;
      for (int i = 0; i < m; ++i) rank += (tie[i] < mk) ? 1 : 0;
      if (rank < r) {
        uint32_t p = (uint32_t)mk & 0x3FFFFu;
        atomicOr((unsigned long long*)&bg[p >> 6], 1ull << (p & 63));
      }
    }
  } else {
    // ---------------- fg path ----------------
    int b = blockIdx.x - BATCH;
    uint32_t E = Ea[b];
    if (E <= (uint32_t)NSEED) return;   // compose reads bmE directly
    uint64_t* lbuf = pool;              // u64[2048]
    const uint64_t* eb = bmE + (size_t)b * WPI;
    uint64_t* ob = bmF + (size_t)b * WPI;
    for (int i = t; i < WPI; i += 1024) ob[i] = 0;
    if (t == 0) { lcnt = 0; tcnt = 0; }
    __syncthreads();
    float tvf = floorf((1.0f - (float)MARGIN / (float)E) * 8388608.0f);
    uint32_t T = (uint32_t)fmaxf(tvf, 0.0f);
    uint32_t k0 = keys[b * 4 + 0], k1 = keys[b * 4 + 1];
    int lane = t & 63;
    for (int k = 0; k < HW / 1024; ++k) {
      uint32_t p = (uint32_t)(k * 1024 + t);
      uint64_t wbits = eb[p >> 6];
      if ((wbits >> lane) & 1ull) {
        uint32_t v = score_bits(k0, k1, p) >> 9;
        if (v >= T) {
          uint32_t pos = atomicAdd(&lcnt, 1u);
          uint64_t key = (((uint64_t)((~v) & 0x7FFFFFu)) << 18) | p;
          if (pos < (uint32_t)LBUF) lbuf[pos] = key;
          else { uint32_t gp = atomicAdd(&cnt_fg[b], 1u);
                 if (gp < (uint32_t)CAP2) list_fg[(size_t)b * CAP2 + gp] = key; }
        }
      }
    }
    __syncthreads();
    int m2 = min((int)lcnt, LBUF);
    if (t == 0) gbase = atomicAdd(&cnt_fg[b], (uint32_t)m2);
    __syncthreads();
    for (int i = t; i < m2; i += 1024) {
      uint32_t pos = gbase + (uint32_t)i;
      if (pos < (uint32_t)CAP2) list_fg[(size_t)b * CAP2 + pos] = lbuf[i];
    }
    __syncthreads();
    // exact top-NSEED cut
    int n = min((int)cnt_fg[b], CAP2);
    if (n == 0) return;
    uint32_t target = (uint32_t)min(NSEED, n);
    const uint64_t* lb = list_fg + (size_t)b * CAP2;
    uint64_t K0 = (t < n)        ? lb[t]        : 0;
    uint64_t K1 = (t + 1024 < n) ? lb[t + 1024] : 0;
    uint64_t K2 = (t + 2048 < n) ? lb[t + 2048] : 0;
    uint64_t K3 = (t + 3072 < n) ? lb[t + 3072] : 0;
    for (int i = t; i < 4096; i += 1024) h[i] = 0;
    __syncthreads();
    if (t < n)        atomicAdd(&h[(uint32_t)(K0 >> 29)], 1u);
    if (t + 1024 < n) atomicAdd(&h[(uint32_t)(K1 >> 29)], 1u);
    if (t + 2048 < n) atomicAdd(&h[(uint32_t)(K2 >> 29)], 1u);
    if (t + 3072 < n) atomicAdd(&h[(uint32_t)(K3 >> 29)], 1u);
    __syncthreads();
    if (t < 256) {
      uint32_t s = 0;
#pragma unroll
      for (int i = 0; i < 16; ++i) s += h[t * 16 + i];
      S[t] = s;
    }
    __syncthreads();
    for (int st = 1; st < 256; st <<= 1) {
      uint32_t v = 0;
      if (t < 256 && t >= st) v = S[t - st];
      __syncthreads();
      if (t < 256) S[t] += v;
      __syncthreads();
    }
    if (t < 256) {
      uint32_t before = (t == 0) ? 0u : S[t - 1];
      if (S[t] >= target && before < target) {
        uint32_t acc = before;
        for (int i = 0; i < 16; ++i) {
          uint32_t c = h[t * 16 + i];
          if (acc + c >= target) { sb2 = (uint32_t)(t * 16 + i); sr2 = target - acc; break; }
          acc += c;
        }
      }
    }
    __syncthreads();
    uint32_t b2 = sb2, r2 = sr2;
#define PROC(KK, VALID) \
    if (VALID) { \
      uint32_t bin = (uint32_t)((KK) >> 29); \
      if (bin < b2) { \
        uint32_t p = (uint32_t)(KK) & 0x3FFFFu; \
        atomicOr((unsigned long long*)&ob[p >> 6], 1ull << (p & 63)); \
      } else if (bin == b2) { \
        uint32_t pos = atomicAdd(&tcnt, 1u); \
        if (pos < 1024u) tie[pos] = (KK); \
      } \
    }
    PROC(K0, t < n) PROC(K1, t + 1024 < n) PROC(K2, t + 2048 < n) PROC(K3, t + 3072 < n)
#undef PROC
    __syncthreads();
    int m = min((int)tcnt, 1024);
    int r = min((int)r2, m);
    if (t < m) {
      uint64_t mk = tie[t];
      int rank = 0;
      for (int i = 0; i < m; ++i) rank += (tie[i] < mk) ? 1 : 0;
      if (rank < r) {
        uint32_t p = (uint32_t)mk & 0x3FFFFu;
        atomicOr((unsigned long long*)&ob[p >> 6], 1ull << (p & 63));
      }
    }
  }
}

// -------- compose v2: per 8-row stripe, compute 64 dilated words ONCE in LDS,
//          then emit 1024 coalesced int4 stores. Kills 16x redundant work. ----
__global__ __launch_bounds__(256) void k_compose2(const uint64_t* __restrict__ bmE,
                                                  const uint64_t* __restrict__ bmF,
                                                  const uint64_t* __restrict__ G,
                                                  const uint32_t* __restrict__ Ea,
                                                  int* __restrict__ out) {
  __shared__ uint64_t FdS[64], BdS[64];
  int blk = blockIdx.x;                 // 128 images * 64 row-groups
  int b = blk >> 6, rg = blk & 63;
  int t = threadIdx.x;
  const uint64_t* Fsrc = (Ea[b] <= (uint32_t)NSEED) ? bmE : bmF;
  const uint64_t* Fb = Fsrc + (size_t)b * WPI;
  const uint64_t* Gb = G + (size_t)b * WPI;
  if (t < 128) {
    const uint64_t* src = (t < 64) ? Fb : Gb;
    int w = t & 63;
    int r = rg * 8 + (w >> 3), c = w & 7;
    uint64_t d = 0;
#pragma unroll
    for (int dr = -1; dr <= 1; ++dr) {
      int rr = r + dr;
      if (rr < 0 || rr >= H) continue;
      int wi = rr * 8 + c;
      uint64_t cur = src[wi];
      uint64_t lf = (c > 0) ? src[wi - 1] : 0ull;
      uint64_t rt = (c < 7) ? src[wi + 1] : 0ull;
      d |= cur | (cur << 1) | (lf >> 63) | (cur >> 1) | (rt << 63);
    }
    if (t < 64) FdS[w] = d; else BdS[w] = d;
  }
  __syncthreads();
  int4* ob = (int4*)out + ((size_t)b * HW + (size_t)rg * 4096) / 4;
  for (int i = t; i < 1024; i += 256) {
    int w = i >> 4, sub = i & 15;
    uint64_t Fd = FdS[w], Bd = BdS[w];
    uint64_t ov = Fd & Bd;
    Fd &= ~ov; Bd &= ~ov;
    int sh = sub * 4;
    int4 o;
    o.x = ((Fd >> (sh + 0)) & 1ull) ? 1 : (((Bd >> (sh + 0)) & 1ull) ? 0 : -255);
    o.y = ((Fd >> (sh + 1)) & 1ull) ? 1 : (((Bd >> (sh + 1)) & 1ull) ? 0 : -255);
    o.z = ((Fd >> (sh + 2)) & 1ull) ? 1 : (((Bd >> (sh + 2)) & 1ull) ? 0 : -255);
    o.w = ((Fd >> (sh + 3)) & 1ull) ? 1 : (((Bd >> (sh + 3)) & 1ull) ? 0 : -255);
    ob[i] = o;
  }
}

extern "C" void kernel_launch(void* const* d_in, const int* in_sizes, int n_in,
                              void* d_out, int out_size, void* d_ws, size_t ws_size,
                              hipStream_t stream) {
  (void)in_sizes; (void)n_in; (void)out_size; (void)ws_size;
  const float* x = (const float*)d_in[0];
  int* out = (int*)d_out;
  char* ws = (char*)d_ws;

  // g (u16 bins, 64 MB) lives in the OUTPUT buffer (128 MB): written by
  // k_binify, read only by k_main, fully overwritten by k_compose2 at the end.
  u16* g = (u16*)d_out;

  // ---- workspace layout (no host memset needed) ----
  uint32_t* keys   = (uint32_t*)(ws + 0);       // 2048
  uint32_t* kbg    = (uint32_t*)(ws + 2048);    // 512
  uint32_t* r1a    = (uint32_t*)(ws + 3584);
  uint32_t* Tbg    = (uint32_t*)(ws + 4096);
  uint32_t* Efg    = (uint32_t*)(ws + 4608);
  uint32_t* cnt_fg = (uint32_t*)(ws + 5120);
  uint32_t* cnt_be = (uint32_t*)(ws + 5632);
  uint32_t* cnt_bg = (uint32_t*)(ws + 6144);
  uint32_t* gh      = (uint32_t*)(ws + 8192);                      // 8 MB
  uint64_t* bmG     = (uint64_t*)(ws + 8192 + 8388608);            // 4 MB
  uint64_t* list    = (uint64_t*)(ws + 8192 + 8388608 + 4194304);  // 4 MB (bg)
  uint64_t* list_be = (uint64_t*)(ws + 8192 + 8388608 + 8388608);  // 1 MB
  uint64_t* bmE     = (uint64_t*)(ws + 8192 + 8388608 + 9437184);  // 4 MB
  uint64_t* bmF     = (uint64_t*)(ws + 8192 + 8388608 + 13631488); // 4 MB
  uint64_t* list_fg = (uint64_t*)gh;   // gh dead after k_main prologue; reuse

  k_binify   <<<BATCH * 4, 1024, 0, stream>>>((const float4*)x, g, gh, keys, kbg,
                                              Tbg, Efg, cnt_fg, cnt_be, cnt_bg);
  k_main     <<<BATCH * 4, 1024, 0, stream>>>(g, x, gh, kbg, Tbg, keys, r1a,
                                              Efg, cnt_bg, list, cnt_be, list_be, bmE);
  k_select   <<<BATCH * 2, 1024, 0, stream>>>(r1a, cnt_be, list_be, Tbg, keys,
                                              cnt_bg, list, bmG,
                                              Efg, cnt_fg, list_fg, bmE, bmF);
  k_compose2 <<<BATCH * 64, 256, 0, stream>>>(bmE, bmF, bmG, Efg, out);
}